// Round 3
// baseline (6996.981 us; speedup 1.0000x reference)
//
#include <hip/hip_runtime.h>
#include <hip/hip_bf16.h>
#include <math.h>

// Problem constants (B=64, N=197, D=768, NH=8, HID=3072).
// Global inputs/outputs: fp32 (per reference). Workspace intermediates: bf16
// (ws budget: round-1's 349 MB fp32 layout faulted; round-2's 174 MB bf16
// layout ran -> 175 MB <= ws_size < 349 MB, so intermediates must be bf16).
#define MROWS (64*197)   // 12608 rows
#define DMODEL 768
#define DHID   3072

typedef __hip_bfloat16 bf16;

__device__ __forceinline__ float b2f(bf16 v) { return __bfloat162float(v); }
__device__ __forceinline__ float tof(float v) { return v; }
__device__ __forceinline__ float tof(bf16 v) { return __bfloat162float(v); }
__device__ __forceinline__ unsigned short f2bu(float f) {
    bf16 h = __float2bfloat16(f);
    return *reinterpret_cast<unsigned short*>(&h);
}
// 4 consecutive bf16 (8B aligned) -> float4
__device__ __forceinline__ float4 ldb4(const bf16* p) {
    uint2 u = *(const uint2*)p;
    float4 r;
    r.x = __uint_as_float(u.x << 16);
    r.y = __uint_as_float(u.x & 0xffff0000u);
    r.z = __uint_as_float(u.y << 16);
    r.w = __uint_as_float(u.y & 0xffff0000u);
    return r;
}
__device__ __forceinline__ float4 ld4(const float* p) { return *(const float4*)p; }
__device__ __forceinline__ float4 ld4(const bf16* p)  { return ldb4(p); }
__device__ __forceinline__ void st4(bf16* p, float a, float b, float c, float d) {
    ushort4 u = make_ushort4(f2bu(a), f2bu(b), f2bu(c), f2bu(d));
    *(ushort4*)p = u;
}
__device__ __forceinline__ void st4(float* p, float a, float b, float c, float d) {
    *(float4*)p = make_float4(a, b, c, d);
}
__device__ __forceinline__ float gelu_exact(float v) {
    return 0.5f * v * (1.0f + erff(v * 0.70710678118654752f));
}

// ---------------- LayerNorm (one block per row); in: fp32 or bf16, out: bf16 ----
template<typename TIN>
__global__ __launch_bounds__(256) void ln_kernel(const TIN* __restrict__ in,
        const float* __restrict__ g, const float* __restrict__ b,
        bf16* __restrict__ out, int Dg) {
    int row = blockIdx.x;
    const TIN* xr = in + (size_t)row * Dg;
    bf16* yr = out + (size_t)row * Dg;
    float s = 0.f, s2 = 0.f;
    for (int c = threadIdx.x; c < Dg; c += 256) { float v = tof(xr[c]); s += v; s2 += v * v; }
    __shared__ float r1[4], r2[4];
    for (int off = 32; off; off >>= 1) { s += __shfl_down(s, off, 64); s2 += __shfl_down(s2, off, 64); }
    if ((threadIdx.x & 63) == 0) { r1[threadIdx.x >> 6] = s; r2[threadIdx.x >> 6] = s2; }
    __syncthreads();
    s  = r1[0] + r1[1] + r1[2] + r1[3];
    s2 = r2[0] + r2[1] + r2[2] + r2[3];
    float mean = s / Dg;
    float var  = s2 / Dg - mean * mean;
    float rstd = rsqrtf(var + 1e-5f);
    for (int c = threadIdx.x; c < Dg; c += 256)
        yr[c] = __float2bfloat16((tof(xr[c]) - mean) * rstd * g[c] + b[c]);
}

// ---------------- GEMM: C[M,N] = A[M,K] @ W[N,K]^T + bias, epilogue ----------------
// A: bf16 (ws). W: fp32 (global weights). bias: fp32. resid: bf16 (ws). C: bf16 or fp32.
// MODE 0: +bias   MODE 1: +bias, gelu   MODE 2: +bias, +resid
template<int MODE, typename TC>
__global__ __launch_bounds__(256) void gemm_bt(const bf16* __restrict__ A,
        const float* __restrict__ W, const float* __restrict__ bias,
        const bf16* __restrict__ resid, TC* __restrict__ C,
        int Mr, int Nc, int Kc)
{
    __shared__ float As[16][128];
    __shared__ float Ws[16][128];
    const int tid = threadIdx.x;
    const int tx = tid & 15, ty = tid >> 4;
    const int m0 = blockIdx.y * 128, n0 = blockIdx.x * 128;
    const int lr = tid >> 2;          // 0..63
    const int lk = (tid & 3) << 2;    // 0,4,8,12 (elements)
    float acc[2][2][4][4];
#pragma unroll
    for (int a = 0; a < 2; ++a)
#pragma unroll
        for (int bq = 0; bq < 2; ++bq)
#pragma unroll
            for (int i = 0; i < 4; ++i)
#pragma unroll
                for (int j = 0; j < 4; ++j) acc[a][bq][i][j] = 0.f;

    for (int k0 = 0; k0 < Kc; k0 += 16) {
        float4 a0 = make_float4(0, 0, 0, 0), a1 = make_float4(0, 0, 0, 0);
        int mA = m0 + lr;
        if (mA < Mr)        a0 = ld4(A + (size_t)mA * Kc + k0 + lk);
        if (mA + 64 < Mr)   a1 = ld4(A + (size_t)(mA + 64) * Kc + k0 + lk);
        float4 b0 = ld4(W + (size_t)(n0 + lr) * Kc + k0 + lk);
        float4 b1 = ld4(W + (size_t)(n0 + lr + 64) * Kc + k0 + lk);
        __syncthreads();   // previous tile's compute done before LDS overwrite
        As[lk + 0][lr] = a0.x; As[lk + 1][lr] = a0.y; As[lk + 2][lr] = a0.z; As[lk + 3][lr] = a0.w;
        As[lk + 0][lr + 64] = a1.x; As[lk + 1][lr + 64] = a1.y; As[lk + 2][lr + 64] = a1.z; As[lk + 3][lr + 64] = a1.w;
        Ws[lk + 0][lr] = b0.x; Ws[lk + 1][lr] = b0.y; Ws[lk + 2][lr] = b0.z; Ws[lk + 3][lr] = b0.w;
        Ws[lk + 0][lr + 64] = b1.x; Ws[lk + 1][lr + 64] = b1.y; Ws[lk + 2][lr + 64] = b1.z; Ws[lk + 3][lr + 64] = b1.w;
        __syncthreads();
#pragma unroll
        for (int kk = 0; kk < 16; ++kk) {
            float4 av0 = *(const float4*)&As[kk][ty << 2];
            float4 av1 = *(const float4*)&As[kk][64 + (ty << 2)];
            float4 bv0 = *(const float4*)&Ws[kk][tx << 2];
            float4 bv1 = *(const float4*)&Ws[kk][64 + (tx << 2)];
            float am[2][4] = {{av0.x, av0.y, av0.z, av0.w}, {av1.x, av1.y, av1.z, av1.w}};
            float bn[2][4] = {{bv0.x, bv0.y, bv0.z, bv0.w}, {bv1.x, bv1.y, bv1.z, bv1.w}};
#pragma unroll
            for (int mg = 0; mg < 2; ++mg)
#pragma unroll
                for (int i = 0; i < 4; ++i)
#pragma unroll
                    for (int ng = 0; ng < 2; ++ng)
#pragma unroll
                        for (int j = 0; j < 4; ++j)
                            acc[mg][ng][i][j] = fmaf(am[mg][i], bn[ng][j], acc[mg][ng][i][j]);
        }
    }
#pragma unroll
    for (int mg = 0; mg < 2; ++mg)
#pragma unroll
        for (int i = 0; i < 4; ++i) {
            int row = m0 + mg * 64 + (ty << 2) + i;
            if (row >= Mr) continue;
#pragma unroll
            for (int ng = 0; ng < 2; ++ng) {
                int col = n0 + ng * 64 + (tx << 2);   // 4 consecutive cols, aligned
                float v[4];
                float4 rs = make_float4(0, 0, 0, 0);
                if (MODE == 2) rs = ldb4(resid + (size_t)row * Nc + col);
                float r4[4] = {rs.x, rs.y, rs.z, rs.w};
#pragma unroll
                for (int j = 0; j < 4; ++j) {
                    v[j] = acc[mg][ng][i][j] + bias[col + j];
                    if (MODE == 1) v[j] = gelu_exact(v[j]);
                    if (MODE == 2) v[j] += r4[j];
                }
                st4(C + (size_t)row * Nc + col, v[0], v[1], v[2], v[3]);
            }
        }
}

// ---------------- Attention: one block per (b,h,q); qkv/ctx bf16 (ws) ----------------
// qkv row layout: row (b*197+n), col t*768 + h*96 + d, t in {q,k,v}
__global__ __launch_bounds__(256) void attn_kernel(const bf16* __restrict__ qkv,
        bf16* __restrict__ ctx) {
    const int N = 197;
    int idx = blockIdx.x;
    int q = idx % N;
    int bh = idx / N;
    int h = bh & 7;
    int b = bh >> 3;
    const bf16* base = qkv + (size_t)b * N * 2304;
    __shared__ float qs[96];
    __shared__ float sc[197];
    __shared__ float red[4];
    int tid = threadIdx.x;
    if (tid < 96) qs[tid] = b2f(base[(size_t)q * 2304 + h * 96 + tid]);
    __syncthreads();
    float s = -1e30f;
    if (tid < N) {
        const bf16* kr = base + (size_t)tid * 2304 + 768 + h * 96;
        float acc = 0.f;
#pragma unroll 8
        for (int d = 0; d < 96; ++d) acc = fmaf(qs[d], b2f(kr[d]), acc);
        acc *= 0.10206207261596577f;  // 96^-0.5
        sc[tid] = acc;
        s = acc;
    }
    for (int off = 32; off; off >>= 1) s = fmaxf(s, __shfl_down(s, off, 64));
    if ((tid & 63) == 0) red[tid >> 6] = s;
    __syncthreads();
    float mx = fmaxf(fmaxf(red[0], red[1]), fmaxf(red[2], red[3]));
    float e = 0.f;
    if (tid < N) e = expf(sc[tid] - mx);
    __syncthreads();   // everyone done reading red[] / sc[]
    if (tid < N) sc[tid] = e;
    float t2 = e;
    for (int off = 32; off; off >>= 1) t2 += __shfl_down(t2, off, 64);
    if ((tid & 63) == 0) red[tid >> 6] = t2;
    __syncthreads();
    float inv = 1.f / (red[0] + red[1] + red[2] + red[3]);
    if (tid < 96) {
        const bf16* vb = base + 1536 + h * 96 + tid;
        float acc = 0.f;
        for (int j = 0; j < N; ++j) acc = fmaf(sc[j], b2f(vb[(size_t)j * 2304]), acc);
        ctx[((size_t)(b * N + q)) * 768 + h * 96 + tid] = __float2bfloat16(acc * inv);
    }
}

// ---------------- SO(8) adapter tail: rotate + err + LN + residuals ----------------
// y = rot(xp) + xin;  out = LN(y)*g + bta + xin (+ xouter if OUTER)
// err per row: FINAL=false -> e_acc[row] = e; FINAL=true -> e_out[row] = e_acc[row] + e
// xp/xin/out: bf16 (ws). xouter/eps/scale/g/bta: fp32 (global). e_*: fp32.
// Dynamic LDS: (Dg + 80) floats. Safe for out == xin (in-place).
template<bool OUTER, bool FINAL>
__global__ __launch_bounds__(256) void adapter_finish(
        const bf16* __restrict__ xp, const bf16* __restrict__ xin,
        const float* __restrict__ xouter, const float* __restrict__ eps,
        const float* __restrict__ scale_p, const float* __restrict__ g,
        const float* __restrict__ bta, bf16* __restrict__ out,
        float* __restrict__ e_acc, float* __restrict__ e_out, int Dg)
{
    extern __shared__ float smem[];
    float* y = smem;            // Dg
    float* diff2 = smem + Dg;   // 64
    float* red = diff2 + 64;    // 8 head-norms
    float* r1 = red + 8;        // 4
    float* r2 = red + 12;       // 4
    int row = blockIdx.x;
    int hd = Dg >> 3;           // 96 or 384
    const bf16* xpr = xp + (size_t)row * Dg;
    const bf16* xir = xin + (size_t)row * Dg;
    int tid = threadIdx.x;
    if (tid < 64) {
        int hh = tid >> 3, i = tid & 7, p = i >> 1;
        float ang = eps[((size_t)row * 8 + hh) * 4 + p] * scale_p[0];
        float c = cosf(ang), sn = sinf(ang);
        int base = hh * hd;
        float ev = b2f(xpr[base + 2 * p]), od = b2f(xpr[base + 2 * p + 1]);
        float r = (i & 1) ? (ev * sn + od * c) : (ev * c - od * sn);
        float d = r - b2f(xpr[base + i]);
        diff2[tid] = d * d;
        y[base + i] = r + b2f(xir[base + i]);
    }
    for (int c0 = tid; c0 < Dg; c0 += 256) {
        if ((c0 % hd) >= 8) y[c0] = b2f(xpr[c0]) + b2f(xir[c0]);
    }
    __syncthreads();
    if (tid < 8) {
        float t = 0.f;
#pragma unroll
        for (int i = 0; i < 8; ++i) t += diff2[tid * 8 + i];
        red[tid] = sqrtf(t);
    }
    float s = 0.f, s2 = 0.f;
    for (int c0 = tid; c0 < Dg; c0 += 256) { float v = y[c0]; s += v; s2 += v * v; }
    for (int off = 32; off; off >>= 1) { s += __shfl_down(s, off, 64); s2 += __shfl_down(s2, off, 64); }
    if ((tid & 63) == 0) { r1[tid >> 6] = s; r2[tid >> 6] = s2; }
    __syncthreads();
    s  = r1[0] + r1[1] + r1[2] + r1[3];
    s2 = r2[0] + r2[1] + r2[2] + r2[3];
    float mean = s / Dg;
    float var  = s2 / Dg - mean * mean;
    float rstd = rsqrtf(var + 1e-5f);
    if (tid == 0) {
        float e = (red[0] + red[1] + red[2] + red[3] + red[4] + red[5] + red[6] + red[7]) * 0.125f;
        if (FINAL) e_out[row] = e_acc[row] + e;
        else       e_acc[row] = e;
    }
    bf16* outr = out + (size_t)row * Dg;
    const float* xo = OUTER ? (xouter + (size_t)row * Dg) : nullptr;
    for (int c0 = tid; c0 < Dg; c0 += 256) {
        float v = (y[c0] - mean) * rstd * g[c0] + bta[c0] + b2f(xir[c0]);
        if (OUTER) v += xo[c0];
        outr[c0] = __float2bfloat16(v);
    }
}

extern "C" void kernel_launch(void* const* d_in, const int* in_sizes, int n_in,
                              void* d_out, int out_size, void* d_ws, size_t ws_size,
                              hipStream_t stream) {
    (void)in_sizes; (void)n_in; (void)out_size; (void)ws_size;
    const int M = MROWS;
    const size_t S_D = (size_t)M * DMODEL;
    const size_t S_H = (size_t)M * DHID;

    const float* x      = (const float*)d_in[0];
    const float* qkv_w  = (const float*)d_in[1];
    const float* qkv_b  = (const float*)d_in[2];
    const float* proj_w = (const float*)d_in[3];
    const float* proj_b = (const float*)d_in[4];
    const float* n1g    = (const float*)d_in[5];
    const float* n1b    = (const float*)d_in[6];
    const float* n2g    = (const float*)d_in[7];
    const float* n2b    = (const float*)d_in[8];
    const float* wa     = (const float*)d_in[9];
    const float* ba     = (const float*)d_in[10];
    const float* sca    = (const float*)d_in[11];
    const float* lga    = (const float*)d_in[12];
    const float* lba    = (const float*)d_in[13];
    const float* wm     = (const float*)d_in[14];
    const float* bm     = (const float*)d_in[15];
    const float* scm    = (const float*)d_in[16];
    const float* lgm    = (const float*)d_in[17];
    const float* lbm    = (const float*)d_in[18];
    const float* f1w    = (const float*)d_in[19];
    const float* f1b    = (const float*)d_in[20];
    const float* f2w    = (const float*)d_in[21];
    const float* f2b    = (const float*)d_in[22];
    const float* eps_a  = (const float*)d_in[23];
    const float* eps_m  = (const float*)d_in[24];

    float* out_x = (float*)d_out;          // M*768 fp32
    float* out_e = out_x + S_D;            // M fp32 (e1+e2)

    // Workspace: bf16 R1[M*3072] | bf16 R2[M*3072] | bf16 R3[M*768] | fp32 E[M]  (~174 MB)
    bf16* R1 = (bf16*)d_ws;
    bf16* R2 = R1 + S_H;
    bf16* R3 = R2 + S_H;
    float* E = (float*)(R3 + S_D);         // byte offset (2*S_H+S_D)*2 is %4==0

    dim3 g768(DMODEL / 128, (M + 127) / 128);
    dim3 g2304(2304 / 128, (M + 127) / 128);
    dim3 g3072(DHID / 128, (M + 127) / 128);

    // 1. x1 = LN1(x)                     -> R1
    ln_kernel<float><<<M, 256, 0, stream>>>(x, n1g, n1b, R1, DMODEL);
    // 2. qkv = x1 @ qkv_w^T + b          -> R2 (M,2304)
    gemm_bt<0, bf16><<<g2304, 256, 0, stream>>>(R1, qkv_w, qkv_b, nullptr, R2, M, 2304, DMODEL);
    // 3. attention                        -> ctx in R1
    attn_kernel<<<64 * 8 * 197, 256, 0, stream>>>(R2, R1);
    // 4. ctxp = ctx @ proj_w^T + b       -> R2
    gemm_bt<0, bf16><<<g768, 256, 0, stream>>>(R1, proj_w, proj_b, nullptr, R2, M, DMODEL, DMODEL);
    // 5. xp_a = ctxp @ wa^T + ba         -> R1
    gemm_bt<0, bf16><<<g768, 256, 0, stream>>>(R2, wa, ba, nullptr, R1, M, DMODEL, DMODEL);
    // 6. adapter-A tail: x_new = x + LN(rot(xp_a)+ctxp)+ctxp -> R3; e1 -> E
    adapter_finish<true, false><<<M, 256, (DMODEL + 80) * sizeof(float), stream>>>(
        R1, R2, x, eps_a, sca, lga, lba, R3, E, nullptr, DMODEL);
    // 7. x2 = LN2(x_new)                 -> R2
    ln_kernel<bf16><<<M, 256, 0, stream>>>(R3, n2g, n2b, R2, DMODEL);
    // 8. h = gelu(x2 @ f1w^T + f1b)      -> R1 (M,3072)
    gemm_bt<1, bf16><<<g3072, 256, 0, stream>>>(R2, f1w, f1b, nullptr, R1, M, DHID, DMODEL);
    // 9. xp_m = h @ wm^T + bm            -> R2 (M,3072)
    gemm_bt<0, bf16><<<g3072, 256, 0, stream>>>(R1, wm, bm, nullptr, R2, M, DHID, DHID);
    // 10. adapter-M tail: h2 = LN(rot(xp_m)+h)+h -> R1 (in place); out_e = E + e2
    adapter_finish<false, true><<<M, 256, (DHID + 80) * sizeof(float), stream>>>(
        R2, R1, nullptr, eps_m, scm, lgm, lbm, R1, E, out_e, DHID);
    // 11. out = x_new + h2 @ f2w^T + f2b -> d_out (fp32)
    gemm_bt<2, float><<<g768, 256, 0, stream>>>(R1, f2w, f2b, R3, out_x, M, DMODEL, DHID);
}

// Round 4
// 2209.488 us; speedup vs baseline: 3.1668x; 3.1668x over previous
//
#include <hip/hip_runtime.h>
#include <hip/hip_bf16.h>
#include <math.h>

// Problem constants (B=64, N=197, D=768, NH=8, HID=3072).
// Global inputs/outputs: fp32 (per reference). Workspace intermediates: bf16.
// GEMMs: bf16 MFMA (16x16x32), 128x128 tile, BK=32, m97-style staging.
#define MROWS (64*197)   // 12608 rows
#define DMODEL 768
#define DHID   3072

typedef __hip_bfloat16 bf16;
using bf16x8 = __attribute__((ext_vector_type(8))) short;  // 8 bf16 (4 VGPRs)
using f32x4  = __attribute__((ext_vector_type(4))) float;  // MFMA accumulator

__device__ __forceinline__ float b2f(bf16 v) { return __bfloat162float(v); }
__device__ __forceinline__ float tof(float v) { return v; }
__device__ __forceinline__ float tof(bf16 v) { return __bfloat162float(v); }
__device__ __forceinline__ short f2bs(float f) {
    bf16 h = __float2bfloat16(f);
    return *reinterpret_cast<short*>(&h);
}
// 4 consecutive bf16 (8B aligned) -> float4
__device__ __forceinline__ float4 ldb4(const bf16* p) {
    uint2 u = *(const uint2*)p;
    float4 r;
    r.x = __uint_as_float(u.x << 16);
    r.y = __uint_as_float(u.x & 0xffff0000u);
    r.z = __uint_as_float(u.y << 16);
    r.w = __uint_as_float(u.y & 0xffff0000u);
    return r;
}
__device__ __forceinline__ float gelu_exact(float v) {
    return 0.5f * v * (1.0f + erff(v * 0.70710678118654752f));
}
__device__ __forceinline__ void st1(bf16* p, float v) { *p = __float2bfloat16(v); }
__device__ __forceinline__ void st1(float* p, float v) { *p = v; }

// async global(16B) -> LDS, gfx950 width-16 variant
__device__ __forceinline__ void gl_lds16(const short* g, short* l) {
    __builtin_amdgcn_global_load_lds(
        (const __attribute__((address_space(1))) void*)g,
        (__attribute__((address_space(3))) void*)l, 16, 0, 0);
}

// ---------------- LayerNorm (one block per row); in: fp32 or bf16, out: bf16 ----
template<typename TIN>
__global__ __launch_bounds__(256) void ln_kernel(const TIN* __restrict__ in,
        const float* __restrict__ g, const float* __restrict__ b,
        bf16* __restrict__ out, int Dg) {
    int row = blockIdx.x;
    const TIN* xr = in + (size_t)row * Dg;
    bf16* yr = out + (size_t)row * Dg;
    float s = 0.f, s2 = 0.f;
    for (int c = threadIdx.x; c < Dg; c += 256) { float v = tof(xr[c]); s += v; s2 += v * v; }
    __shared__ float r1[4], r2[4];
    for (int off = 32; off; off >>= 1) { s += __shfl_down(s, off, 64); s2 += __shfl_down(s2, off, 64); }
    if ((threadIdx.x & 63) == 0) { r1[threadIdx.x >> 6] = s; r2[threadIdx.x >> 6] = s2; }
    __syncthreads();
    s  = r1[0] + r1[1] + r1[2] + r1[3];
    s2 = r2[0] + r2[1] + r2[2] + r2[3];
    float mean = s / Dg;
    float var  = s2 / Dg - mean * mean;
    float rstd = rsqrtf(var + 1e-5f);
    for (int c = threadIdx.x; c < Dg; c += 256)
        yr[c] = __float2bfloat16((tof(xr[c]) - mean) * rstd * g[c] + b[c]);
}

// ---------------- MFMA GEMM: C[M,N] = A[M,K](bf16) @ W[N,K](fp32)^T + bias ------
// 128x128 tile, BK=32, 4 waves (2x2 of 64x64), 4x4 16x16x32 MFMA per wave.
// A staged via global_load_lds width=16; W staged via float4 loads + cvt + ds_write.
// MODE 0: +bias   MODE 1: +bias,gelu   MODE 2: +bias,+resid(bf16)
template<int MODE, typename TC>
__global__ __launch_bounds__(256) void gemm_mfma(const short* __restrict__ A,
        const float* __restrict__ W, const float* __restrict__ bias,
        const bf16* __restrict__ resid, TC* __restrict__ C,
        int Mr, int Nc, int Kc)
{
    __shared__ short Abuf[128 * 32];   // [row][k] row-major, 8 KB
    __shared__ short Bbuf[128 * 32];   // [n][k]  row-major, 8 KB
    const int tid  = threadIdx.x;
    const int lane = tid & 63, wave = tid >> 6;
    const int wm = wave & 1, wn = wave >> 1;
    const int quad = lane >> 4, l16 = lane & 15;
    const int m0 = blockIdx.y * 128, n0 = blockIdx.x * 128;

    f32x4 acc[4][4];
#pragma unroll
    for (int i = 0; i < 4; ++i)
#pragma unroll
        for (int j = 0; j < 4; ++j) acc[i][j] = (f32x4){0.f, 0.f, 0.f, 0.f};

    const int brow = tid >> 3;       // 0..31  (row within 32-row sweep)
    const int bk   = (tid & 7) * 4;  // k offset 0..28

    for (int k0 = 0; k0 < Kc; k0 += 32) {
        // B (weights, fp32): coalesced loads issued before barrier to overlap MFMA
        float4 wv[4];
#pragma unroll
        for (int s = 0; s < 4; ++s)
            wv[s] = *(const float4*)(W + (size_t)(n0 + s * 32 + brow) * Kc + k0 + bk);
        __syncthreads();   // prior tile's MFMA reads done before LDS overwrite
        // A: async 16B direct-to-LDS, 2 per thread. chunk c covers row c>>2, k (c&3)*8
#pragma unroll
        for (int q = 0; q < 2; ++q) {
            int c = q * 256 + tid;
            int rowA = m0 + (c >> 2);
            if (rowA > Mr - 1) rowA = Mr - 1;   // clamp tail tile (discarded at store)
            gl_lds16(A + (size_t)rowA * Kc + k0 + (c & 3) * 8, Abuf + c * 8);
        }
        // B: convert fp32->bf16, write 8B chunks
#pragma unroll
        for (int s = 0; s < 4; ++s) {
            short4 h;
            h.x = f2bs(wv[s].x); h.y = f2bs(wv[s].y);
            h.z = f2bs(wv[s].z); h.w = f2bs(wv[s].w);
            *(short4*)(Bbuf + (s * 32 + brow) * 32 + bk) = h;
        }
        __syncthreads();   // drains vmcnt (global_load_lds) + lgkm (ds_write)
        // fragments: lane holds [m=l16][k=quad*8..+7]
        bf16x8 fa[4], fb[4];
#pragma unroll
        for (int i = 0; i < 4; ++i)
            fa[i] = *(const bf16x8*)(Abuf + (wm * 64 + i * 16 + l16) * 32 + quad * 8);
#pragma unroll
        for (int j = 0; j < 4; ++j)
            fb[j] = *(const bf16x8*)(Bbuf + (wn * 64 + j * 16 + l16) * 32 + quad * 8);
#pragma unroll
        for (int i = 0; i < 4; ++i)
#pragma unroll
            for (int j = 0; j < 4; ++j)
                acc[i][j] = __builtin_amdgcn_mfma_f32_16x16x32_bf16(fa[i], fb[j], acc[i][j], 0, 0, 0);
    }

    // Epilogue. C/D layout: col = lane&15, row = quad*4 + reg  [m89/m91 verified]
#pragma unroll
    for (int i = 0; i < 4; ++i)
#pragma unroll
        for (int r = 0; r < 4; ++r) {
            int row = m0 + wm * 64 + i * 16 + quad * 4 + r;
            if (row >= Mr) continue;
#pragma unroll
            for (int j = 0; j < 4; ++j) {
                int col = n0 + wn * 64 + j * 16 + l16;
                float v = acc[i][j][r] + bias[col];
                if (MODE == 1) v = gelu_exact(v);
                if (MODE == 2) v += b2f(resid[(size_t)row * Nc + col]);
                st1(C + (size_t)row * Nc + col, v);
            }
        }
}

// ---------------- Attention: one block per (b,h,q); qkv/ctx bf16 (ws) ----------------
__global__ __launch_bounds__(256) void attn_kernel(const bf16* __restrict__ qkv,
        bf16* __restrict__ ctx) {
    const int N = 197;
    int idx = blockIdx.x;
    int q = idx % N;
    int bh = idx / N;
    int h = bh & 7;
    int b = bh >> 3;
    const bf16* base = qkv + (size_t)b * N * 2304;
    __shared__ float qs[96];
    __shared__ float sc[197];
    __shared__ float red[4];
    int tid = threadIdx.x;
    if (tid < 96) qs[tid] = b2f(base[(size_t)q * 2304 + h * 96 + tid]);
    __syncthreads();
    float s = -1e30f;
    if (tid < N) {
        const bf16* kr = base + (size_t)tid * 2304 + 768 + h * 96;
        float acc = 0.f;
#pragma unroll 8
        for (int d = 0; d < 96; ++d) acc = fmaf(qs[d], b2f(kr[d]), acc);
        acc *= 0.10206207261596577f;  // 96^-0.5
        sc[tid] = acc;
        s = acc;
    }
    for (int off = 32; off; off >>= 1) s = fmaxf(s, __shfl_down(s, off, 64));
    if ((tid & 63) == 0) red[tid >> 6] = s;
    __syncthreads();
    float mx = fmaxf(fmaxf(red[0], red[1]), fmaxf(red[2], red[3]));
    float e = 0.f;
    if (tid < N) e = expf(sc[tid] - mx);
    __syncthreads();
    if (tid < N) sc[tid] = e;
    float t2 = e;
    for (int off = 32; off; off >>= 1) t2 += __shfl_down(t2, off, 64);
    if ((tid & 63) == 0) red[tid >> 6] = t2;
    __syncthreads();
    float inv = 1.f / (red[0] + red[1] + red[2] + red[3]);
    if (tid < 96) {
        const bf16* vb = base + 1536 + h * 96 + tid;
        float acc = 0.f;
        for (int j = 0; j < N; ++j) acc = fmaf(sc[j], b2f(vb[(size_t)j * 2304]), acc);
        ctx[((size_t)(b * N + q)) * 768 + h * 96 + tid] = __float2bfloat16(acc * inv);
    }
}

// ---------------- SO(8) adapter tail: rotate + err + LN + residuals ----------------
template<bool OUTER, bool FINAL>
__global__ __launch_bounds__(256) void adapter_finish(
        const bf16* __restrict__ xp, const bf16* __restrict__ xin,
        const float* __restrict__ xouter, const float* __restrict__ eps,
        const float* __restrict__ scale_p, const float* __restrict__ g,
        const float* __restrict__ bta, bf16* __restrict__ out,
        float* __restrict__ e_acc, float* __restrict__ e_out, int Dg)
{
    extern __shared__ float smem[];
    float* y = smem;            // Dg
    float* diff2 = smem + Dg;   // 64
    float* red = diff2 + 64;    // 8 head-norms
    float* r1 = red + 8;        // 4
    float* r2 = red + 12;       // 4
    int row = blockIdx.x;
    int hd = Dg >> 3;           // 96 or 384
    const bf16* xpr = xp + (size_t)row * Dg;
    const bf16* xir = xin + (size_t)row * Dg;
    int tid = threadIdx.x;
    if (tid < 64) {
        int hh = tid >> 3, i = tid & 7, p = i >> 1;
        float ang = eps[((size_t)row * 8 + hh) * 4 + p] * scale_p[0];
        float c = cosf(ang), sn = sinf(ang);
        int base = hh * hd;
        float ev = b2f(xpr[base + 2 * p]), od = b2f(xpr[base + 2 * p + 1]);
        float r = (i & 1) ? (ev * sn + od * c) : (ev * c - od * sn);
        float d = r - b2f(xpr[base + i]);
        diff2[tid] = d * d;
        y[base + i] = r + b2f(xir[base + i]);
    }
    for (int c0 = tid; c0 < Dg; c0 += 256) {
        if ((c0 % hd) >= 8) y[c0] = b2f(xpr[c0]) + b2f(xir[c0]);
    }
    __syncthreads();
    if (tid < 8) {
        float t = 0.f;
#pragma unroll
        for (int i = 0; i < 8; ++i) t += diff2[tid * 8 + i];
        red[tid] = sqrtf(t);
    }
    float s = 0.f, s2 = 0.f;
    for (int c0 = tid; c0 < Dg; c0 += 256) { float v = y[c0]; s += v; s2 += v * v; }
    for (int off = 32; off; off >>= 1) { s += __shfl_down(s, off, 64); s2 += __shfl_down(s2, off, 64); }
    if ((tid & 63) == 0) { r1[tid >> 6] = s; r2[tid >> 6] = s2; }
    __syncthreads();
    s  = r1[0] + r1[1] + r1[2] + r1[3];
    s2 = r2[0] + r2[1] + r2[2] + r2[3];
    float mean = s / Dg;
    float var  = s2 / Dg - mean * mean;
    float rstd = rsqrtf(var + 1e-5f);
    if (tid == 0) {
        float e = (red[0] + red[1] + red[2] + red[3] + red[4] + red[5] + red[6] + red[7]) * 0.125f;
        if (FINAL) e_out[row] = e_acc[row] + e;
        else       e_acc[row] = e;
    }
    bf16* outr = out + (size_t)row * Dg;
    const float* xo = OUTER ? (xouter + (size_t)row * Dg) : nullptr;
    for (int c0 = tid; c0 < Dg; c0 += 256) {
        float v = (y[c0] - mean) * rstd * g[c0] + bta[c0] + b2f(xir[c0]);
        if (OUTER) v += xo[c0];
        outr[c0] = __float2bfloat16(v);
    }
}

extern "C" void kernel_launch(void* const* d_in, const int* in_sizes, int n_in,
                              void* d_out, int out_size, void* d_ws, size_t ws_size,
                              hipStream_t stream) {
    (void)in_sizes; (void)n_in; (void)out_size; (void)ws_size;
    const int M = MROWS;
    const size_t S_D = (size_t)M * DMODEL;
    const size_t S_H = (size_t)M * DHID;

    const float* x      = (const float*)d_in[0];
    const float* qkv_w  = (const float*)d_in[1];
    const float* qkv_b  = (const float*)d_in[2];
    const float* proj_w = (const float*)d_in[3];
    const float* proj_b = (const float*)d_in[4];
    const float* n1g    = (const float*)d_in[5];
    const float* n1b    = (const float*)d_in[6];
    const float* n2g    = (const float*)d_in[7];
    const float* n2b    = (const float*)d_in[8];
    const float* wa     = (const float*)d_in[9];
    const float* ba     = (const float*)d_in[10];
    const float* sca    = (const float*)d_in[11];
    const float* lga    = (const float*)d_in[12];
    const float* lba    = (const float*)d_in[13];
    const float* wm     = (const float*)d_in[14];
    const float* bm     = (const float*)d_in[15];
    const float* scm    = (const float*)d_in[16];
    const float* lgm    = (const float*)d_in[17];
    const float* lbm    = (const float*)d_in[18];
    const float* f1w    = (const float*)d_in[19];
    const float* f1b    = (const float*)d_in[20];
    const float* f2w    = (const float*)d_in[21];
    const float* f2b    = (const float*)d_in[22];
    const float* eps_a  = (const float*)d_in[23];
    const float* eps_m  = (const float*)d_in[24];

    float* out_x = (float*)d_out;          // M*768 fp32
    float* out_e = out_x + S_D;            // M fp32 (e1+e2)

    // Workspace: bf16 R1[M*3072] | bf16 R2[M*3072] | bf16 R3[M*768] | fp32 E[M]  (~174 MB)
    bf16* R1 = (bf16*)d_ws;
    bf16* R2 = R1 + S_H;
    bf16* R3 = R2 + S_H;
    float* E = (float*)(R3 + S_D);

    const int GY = (M + 127) / 128;   // 99

    // 1. x1 = LN1(x)                     -> R1
    ln_kernel<float><<<M, 256, 0, stream>>>(x, n1g, n1b, R1, DMODEL);
    // 2. qkv = x1 @ qkv_w^T + b          -> R2 (M,2304)
    gemm_mfma<0, bf16><<<dim3(2304 / 128, GY), 256, 0, stream>>>(
        (const short*)R1, qkv_w, qkv_b, nullptr, R2, M, 2304, DMODEL);
    // 3. attention                        -> ctx in R1
    attn_kernel<<<64 * 8 * 197, 256, 0, stream>>>(R2, R1);
    // 4. ctxp = ctx @ proj_w^T + b       -> R2
    gemm_mfma<0, bf16><<<dim3(DMODEL / 128, GY), 256, 0, stream>>>(
        (const short*)R1, proj_w, proj_b, nullptr, R2, M, DMODEL, DMODEL);
    // 5. xp_a = ctxp @ wa^T + ba         -> R1
    gemm_mfma<0, bf16><<<dim3(DMODEL / 128, GY), 256, 0, stream>>>(
        (const short*)R2, wa, ba, nullptr, R1, M, DMODEL, DMODEL);
    // 6. adapter-A tail: x_new = x + LN(rot(xp_a)+ctxp)+ctxp -> R3; e1 -> E
    adapter_finish<true, false><<<M, 256, (DMODEL + 80) * sizeof(float), stream>>>(
        R1, R2, x, eps_a, sca, lga, lba, R3, E, nullptr, DMODEL);
    // 7. x2 = LN2(x_new)                 -> R2
    ln_kernel<bf16><<<M, 256, 0, stream>>>(R3, n2g, n2b, R2, DMODEL);
    // 8. h = gelu(x2 @ f1w^T + f1b)      -> R1 (M,3072)
    gemm_mfma<1, bf16><<<dim3(DHID / 128, GY), 256, 0, stream>>>(
        (const short*)R2, f1w, f1b, nullptr, R1, M, DHID, DMODEL);
    // 9. xp_m = h @ wm^T + bm            -> R2 (M,3072)
    gemm_mfma<0, bf16><<<dim3(DHID / 128, GY), 256, 0, stream>>>(
        (const short*)R1, wm, bm, nullptr, R2, M, DHID, DHID);
    // 10. adapter-M tail: h2 = LN(rot(xp_m)+h)+h -> R1 (in place); out_e = E + e2
    adapter_finish<false, true><<<M, 256, (DHID + 80) * sizeof(float), stream>>>(
        R2, R1, nullptr, eps_m, scm, lgm, lbm, R1, E, out_e, DHID);
    // 11. out = x_new + h2 @ f2w^T + f2b -> d_out (fp32)
    gemm_mfma<2, float><<<dim3(DMODEL / 128, GY), 256, 0, stream>>>(
        (const short*)R1, f2w, f2b, R3, out_x, M, DMODEL, DHID);
}

// Round 5
// 1189.058 us; speedup vs baseline: 5.8845x; 1.8582x over previous
//
#include <hip/hip_runtime.h>
#include <hip/hip_bf16.h>
#include <math.h>

// Problem constants (B=64, N=197, D=768, NH=8, HID=3072).
// Global inputs/outputs: fp32 (per reference). Workspace intermediates: bf16.
// GEMMs: bf16 MFMA (16x16x32), 128x128 tile, BK=32, m97-style staging.
// Attention: MFMA flash-style, one block per (b,h), K/V^T staged in LDS.
#define MROWS (64*197)   // 12608 rows
#define DMODEL 768
#define DHID   3072

typedef __hip_bfloat16 bf16;
using bf16x8 = __attribute__((ext_vector_type(8))) short;  // 8 bf16 (4 VGPRs)
using f32x4  = __attribute__((ext_vector_type(4))) float;  // MFMA accumulator

__device__ __forceinline__ float b2f(bf16 v) { return __bfloat162float(v); }
__device__ __forceinline__ float tof(float v) { return v; }
__device__ __forceinline__ float tof(bf16 v) { return __bfloat162float(v); }
__device__ __forceinline__ short f2bs(float f) {
    bf16 h = __float2bfloat16(f);
    return *reinterpret_cast<short*>(&h);
}
// 4 consecutive bf16 (8B aligned) -> float4
__device__ __forceinline__ float4 ldb4(const bf16* p) {
    uint2 u = *(const uint2*)p;
    float4 r;
    r.x = __uint_as_float(u.x << 16);
    r.y = __uint_as_float(u.x & 0xffff0000u);
    r.z = __uint_as_float(u.y << 16);
    r.w = __uint_as_float(u.y & 0xffff0000u);
    return r;
}
__device__ __forceinline__ float gelu_exact(float v) {
    return 0.5f * v * (1.0f + erff(v * 0.70710678118654752f));
}
__device__ __forceinline__ void st1(bf16* p, float v) { *p = __float2bfloat16(v); }
__device__ __forceinline__ void st1(float* p, float v) { *p = v; }

// async global(16B) -> LDS, gfx950 width-16 variant
__device__ __forceinline__ void gl_lds16(const short* g, short* l) {
    __builtin_amdgcn_global_load_lds(
        (const __attribute__((address_space(1))) void*)g,
        (__attribute__((address_space(3))) void*)l, 16, 0, 0);
}

// ---------------- LayerNorm (one block per row); in: fp32 or bf16, out: bf16 ----
template<typename TIN>
__global__ __launch_bounds__(256) void ln_kernel(const TIN* __restrict__ in,
        const float* __restrict__ g, const float* __restrict__ b,
        bf16* __restrict__ out, int Dg) {
    int row = blockIdx.x;
    const TIN* xr = in + (size_t)row * Dg;
    bf16* yr = out + (size_t)row * Dg;
    float s = 0.f, s2 = 0.f;
    for (int c = threadIdx.x; c < Dg; c += 256) { float v = tof(xr[c]); s += v; s2 += v * v; }
    __shared__ float r1[4], r2[4];
    for (int off = 32; off; off >>= 1) { s += __shfl_down(s, off, 64); s2 += __shfl_down(s2, off, 64); }
    if ((threadIdx.x & 63) == 0) { r1[threadIdx.x >> 6] = s; r2[threadIdx.x >> 6] = s2; }
    __syncthreads();
    s  = r1[0] + r1[1] + r1[2] + r1[3];
    s2 = r2[0] + r2[1] + r2[2] + r2[3];
    float mean = s / Dg;
    float var  = s2 / Dg - mean * mean;
    float rstd = rsqrtf(var + 1e-5f);
    for (int c = threadIdx.x; c < Dg; c += 256)
        yr[c] = __float2bfloat16((tof(xr[c]) - mean) * rstd * g[c] + b[c]);
}

// ---------------- MFMA GEMM: C[M,N] = A[M,K](bf16) @ W[N,K](fp32)^T + bias ------
// 128x128 tile, BK=32, 4 waves (2x2 of 64x64), 4x4 16x16x32 MFMA per wave.
// A staged via global_load_lds width=16; W staged via float4 loads + cvt + ds_write.
// MODE 0: +bias   MODE 1: +bias,gelu   MODE 2: +bias,+resid(bf16)
template<int MODE, typename TC>
__global__ __launch_bounds__(256) void gemm_mfma(const short* __restrict__ A,
        const float* __restrict__ W, const float* __restrict__ bias,
        const bf16* __restrict__ resid, TC* __restrict__ C,
        int Mr, int Nc, int Kc)
{
    __shared__ short Abuf[128 * 32];   // [row][k] row-major, 8 KB
    __shared__ short Bbuf[128 * 32];   // [n][k]  row-major, 8 KB
    const int tid  = threadIdx.x;
    const int lane = tid & 63, wave = tid >> 6;
    const int wm = wave & 1, wn = wave >> 1;
    const int quad = lane >> 4, l16 = lane & 15;
    const int m0 = blockIdx.y * 128, n0 = blockIdx.x * 128;

    f32x4 acc[4][4];
#pragma unroll
    for (int i = 0; i < 4; ++i)
#pragma unroll
        for (int j = 0; j < 4; ++j) acc[i][j] = (f32x4){0.f, 0.f, 0.f, 0.f};

    const int brow = tid >> 3;       // 0..31  (row within 32-row sweep)
    const int bk   = (tid & 7) * 4;  // k offset 0..28

    for (int k0 = 0; k0 < Kc; k0 += 32) {
        // B (weights, fp32): coalesced loads issued before barrier to overlap MFMA
        float4 wv[4];
#pragma unroll
        for (int s = 0; s < 4; ++s)
            wv[s] = *(const float4*)(W + (size_t)(n0 + s * 32 + brow) * Kc + k0 + bk);
        __syncthreads();   // prior tile's MFMA reads done before LDS overwrite
        // A: async 16B direct-to-LDS, 2 per thread. chunk c covers row c>>2, k (c&3)*8
#pragma unroll
        for (int q = 0; q < 2; ++q) {
            int c = q * 256 + tid;
            int rowA = m0 + (c >> 2);
            if (rowA > Mr - 1) rowA = Mr - 1;   // clamp tail tile (discarded at store)
            gl_lds16(A + (size_t)rowA * Kc + k0 + (c & 3) * 8, Abuf + c * 8);
        }
        // B: convert fp32->bf16, write 8B chunks
#pragma unroll
        for (int s = 0; s < 4; ++s) {
            short4 h;
            h.x = f2bs(wv[s].x); h.y = f2bs(wv[s].y);
            h.z = f2bs(wv[s].z); h.w = f2bs(wv[s].w);
            *(short4*)(Bbuf + (s * 32 + brow) * 32 + bk) = h;
        }
        __syncthreads();   // drains vmcnt (global_load_lds) + lgkm (ds_write)
        // fragments: lane holds [m=l16][k=quad*8..+7]
        bf16x8 fa[4], fb[4];
#pragma unroll
        for (int i = 0; i < 4; ++i)
            fa[i] = *(const bf16x8*)(Abuf + (wm * 64 + i * 16 + l16) * 32 + quad * 8);
#pragma unroll
        for (int j = 0; j < 4; ++j)
            fb[j] = *(const bf16x8*)(Bbuf + (wn * 64 + j * 16 + l16) * 32 + quad * 8);
#pragma unroll
        for (int i = 0; i < 4; ++i)
#pragma unroll
            for (int j = 0; j < 4; ++j)
                acc[i][j] = __builtin_amdgcn_mfma_f32_16x16x32_bf16(fa[i], fb[j], acc[i][j], 0, 0, 0);
    }

    // Epilogue. C/D layout: col = lane&15, row = quad*4 + reg  [m89/m91 verified]
#pragma unroll
    for (int i = 0; i < 4; ++i)
#pragma unroll
        for (int r = 0; r < 4; ++r) {
            int row = m0 + wm * 64 + i * 16 + quad * 4 + r;
            if (row >= Mr) continue;
#pragma unroll
            for (int j = 0; j < 4; ++j) {
                int col = n0 + wn * 64 + j * 16 + l16;
                float v = acc[i][j][r] + bias[col];
                if (MODE == 1) v = gelu_exact(v);
                if (MODE == 2) v += b2f(resid[(size_t)row * Nc + col]);
                st1(C + (size_t)row * Nc + col, v);
            }
        }
}

// ---------------- Attention (MFMA): one block per (b,h) ----------------
// qkv row layout: row (b*197+n), col t*768 + h*96 + d, t in {q,k,v}
// K staged [224 x 104] (padded, zero-filled); V staged transposed [96 x 232].
// Per wave: q-tiles of 16 rows; S=Q.K^T in C-layout regs; masked softmax with
// shfl_xor row reductions; P -> per-wave LDS (C-layout -> A-layout transform);
// O = P.V^T; scale by 1/rowsum at store. ~121 KB LDS -> 1 block/CU.
__global__ __launch_bounds__(256) void attn_mfma(const bf16* __restrict__ qkv,
        bf16* __restrict__ ctx) {
    const int NS = 197;
    const int KST = 104;   // Kbuf row stride (elems): 2-way bank aliasing only
    const int VST = 232;   // Vt/P row stride (elems): 2-way bank aliasing only
    __shared__ short Kbuf[224 * KST];      // 46.6 KB
    __shared__ short Vt[96 * VST];         // 44.5 KB
    __shared__ short Pbuf[4][16 * VST];    // 29.7 KB (per-wave)
    const int b = blockIdx.x >> 3, h = blockIdx.x & 7;
    const short* base = (const short*)qkv + (size_t)b * NS * 2304 + h * 96;
    const int tid = threadIdx.x;

    // stage K rows (12 x 16B chunks per row), coalesced
    for (int c = tid; c < NS * 12; c += 256) {
        int key = c / 12, dc = c % 12;
        bf16x8 v = *(const bf16x8*)(base + (size_t)key * 2304 + 768 + dc * 8);
        *(bf16x8*)(Kbuf + key * KST + dc * 8) = v;
    }
    for (int c = tid; c < 27 * 12; c += 256) {   // zero pad rows 197..223
        int key = NS + c / 12, dc = c % 12;
        *(bf16x8*)(Kbuf + key * KST + dc * 8) = (bf16x8){0, 0, 0, 0, 0, 0, 0, 0};
    }
    // stage V transposed: 16B coalesced read, 8 scalar LDS scatter writes
    for (int c = tid; c < NS * 12; c += 256) {
        int key = c / 12, dc = c % 12;
        bf16x8 v = *(const bf16x8*)(base + (size_t)key * 2304 + 1536 + dc * 8);
#pragma unroll
        for (int j = 0; j < 8; ++j) Vt[(dc * 8 + j) * VST + key] = v[j];
    }
    for (int c = tid; c < 96 * 27; c += 256) {   // zero pad cols 197..223
        int d = c / 27, key = NS + c % 27;
        Vt[d * VST + key] = 0;
    }
    __syncthreads();

    const int wave = tid >> 6, lane = tid & 63;
    const int quad = lane >> 4, l16 = lane & 15;
    short* P = &Pbuf[wave][0];

    for (int qt = wave; qt < 13; qt += 4) {
        // Q fragments straight from global: A[m=l16][k=quad*8+j]
        int qrow = qt * 16 + l16; if (qrow > NS - 1) qrow = NS - 1;  // clamp tail
        bf16x8 fq[3];
#pragma unroll
        for (int kc = 0; kc < 3; ++kc)
            fq[kc] = *(const bf16x8*)(base + (size_t)qrow * 2304 + kc * 32 + quad * 8);
        // S = Q.K^T  (14 col-tiles x 3 k-chunks)
        f32x4 s[14];
#pragma unroll
        for (int nt = 0; nt < 14; ++nt) {
            s[nt] = (f32x4){0.f, 0.f, 0.f, 0.f};
#pragma unroll
            for (int kc = 0; kc < 3; ++kc) {
                bf16x8 fk = *(const bf16x8*)(Kbuf + (nt * 16 + l16) * KST + kc * 32 + quad * 8);
                s[nt] = __builtin_amdgcn_mfma_f32_16x16x32_bf16(fq[kc], fk, s[nt], 0, 0, 0);
            }
        }
        // masked softmax. C-layout: this lane holds rows quad*4+r, col nt*16+l16
        const float sc = 0.10206207261596577f;   // 96^-0.5
        float mx[4] = {-1e30f, -1e30f, -1e30f, -1e30f};
#pragma unroll
        for (int nt = 0; nt < 14; ++nt) {
            bool valid = nt * 16 + l16 < NS;
#pragma unroll
            for (int r = 0; r < 4; ++r) {
                float v = s[nt][r] * sc;
                s[nt][r] = v;
                if (valid) mx[r] = fmaxf(mx[r], v);
            }
        }
#pragma unroll
        for (int m = 1; m < 16; m <<= 1)
#pragma unroll
            for (int r = 0; r < 4; ++r) mx[r] = fmaxf(mx[r], __shfl_xor(mx[r], m, 64));
        float l[4] = {0.f, 0.f, 0.f, 0.f};
#pragma unroll
        for (int nt = 0; nt < 14; ++nt) {
            bool valid = nt * 16 + l16 < NS;
#pragma unroll
            for (int r = 0; r < 4; ++r) {
                float e = valid ? __expf(s[nt][r] - mx[r]) : 0.f;
                l[r] += e;
                P[(quad * 4 + r) * VST + nt * 16 + l16] = f2bs(e);
            }
        }
#pragma unroll
        for (int m = 1; m < 16; m <<= 1)
#pragma unroll
            for (int r = 0; r < 4; ++r) l[r] += __shfl_xor(l[r], m, 64);
        // wave-private LDS write->read: drain lgkm (lockstep wave, no barrier needed)
        __asm__ volatile("s_waitcnt lgkmcnt(0)" ::: "memory");
        // O = P.V^T  (6 dim-tiles x 7 k-chunks)
        f32x4 o[6];
#pragma unroll
        for (int nt = 0; nt < 6; ++nt) o[nt] = (f32x4){0.f, 0.f, 0.f, 0.f};
#pragma unroll
        for (int kc = 0; kc < 7; ++kc) {
            bf16x8 fp = *(const bf16x8*)(P + l16 * VST + kc * 32 + quad * 8);
#pragma unroll
            for (int nt = 0; nt < 6; ++nt) {
                bf16x8 fv = *(const bf16x8*)(Vt + (nt * 16 + l16) * VST + kc * 32 + quad * 8);
                o[nt] = __builtin_amdgcn_mfma_f32_16x16x32_bf16(fp, fv, o[nt], 0, 0, 0);
            }
        }
        float inv[4];
#pragma unroll
        for (int r = 0; r < 4; ++r) inv[r] = 1.f / l[r];
#pragma unroll
        for (int r = 0; r < 4; ++r) {
            int q = qt * 16 + quad * 4 + r;
            if (q >= NS) continue;
            bf16* orow = ctx + ((size_t)(b * NS + q)) * 768 + h * 96;
#pragma unroll
            for (int nt = 0; nt < 6; ++nt)
                orow[nt * 16 + l16] = __float2bfloat16(o[nt][r] * inv[r]);
        }
    }
}

// ---------------- SO(8) adapter tail: rotate + err + LN + residuals ----------------
template<bool OUTER, bool FINAL>
__global__ __launch_bounds__(256) void adapter_finish(
        const bf16* __restrict__ xp, const bf16* __restrict__ xin,
        const float* __restrict__ xouter, const float* __restrict__ eps,
        const float* __restrict__ scale_p, const float* __restrict__ g,
        const float* __restrict__ bta, bf16* __restrict__ out,
        float* __restrict__ e_acc, float* __restrict__ e_out, int Dg)
{
    extern __shared__ float smem[];
    float* y = smem;            // Dg
    float* diff2 = smem + Dg;   // 64
    float* red = diff2 + 64;    // 8 head-norms
    float* r1 = red + 8;        // 4
    float* r2 = red + 12;       // 4
    int row = blockIdx.x;
    int hd = Dg >> 3;           // 96 or 384
    const bf16* xpr = xp + (size_t)row * Dg;
    const bf16* xir = xin + (size_t)row * Dg;
    int tid = threadIdx.x;
    if (tid < 64) {
        int hh = tid >> 3, i = tid & 7, p = i >> 1;
        float ang = eps[((size_t)row * 8 + hh) * 4 + p] * scale_p[0];
        float c = cosf(ang), sn = sinf(ang);
        int base = hh * hd;
        float ev = b2f(xpr[base + 2 * p]), od = b2f(xpr[base + 2 * p + 1]);
        float r = (i & 1) ? (ev * sn + od * c) : (ev * c - od * sn);
        float d = r - b2f(xpr[base + i]);
        diff2[tid] = d * d;
        y[base + i] = r + b2f(xir[base + i]);
    }
    for (int c0 = tid; c0 < Dg; c0 += 256) {
        if ((c0 % hd) >= 8) y[c0] = b2f(xpr[c0]) + b2f(xir[c0]);
    }
    __syncthreads();
    if (tid < 8) {
        float t = 0.f;
#pragma unroll
        for (int i = 0; i < 8; ++i) t += diff2[tid * 8 + i];
        red[tid] = sqrtf(t);
    }
    float s = 0.f, s2 = 0.f;
    for (int c0 = tid; c0 < Dg; c0 += 256) { float v = y[c0]; s += v; s2 += v * v; }
    for (int off = 32; off; off >>= 1) { s += __shfl_down(s, off, 64); s2 += __shfl_down(s2, off, 64); }
    if ((tid & 63) == 0) { r1[tid >> 6] = s; r2[tid >> 6] = s2; }
    __syncthreads();
    s  = r1[0] + r1[1] + r1[2] + r1[3];
    s2 = r2[0] + r2[1] + r2[2] + r2[3];
    float mean = s / Dg;
    float var  = s2 / Dg - mean * mean;
    float rstd = rsqrtf(var + 1e-5f);
    if (tid == 0) {
        float e = (red[0] + red[1] + red[2] + red[3] + red[4] + red[5] + red[6] + red[7]) * 0.125f;
        if (FINAL) e_out[row] = e_acc[row] + e;
        else       e_acc[row] = e;
    }
    bf16* outr = out + (size_t)row * Dg;
    const float* xo = OUTER ? (xouter + (size_t)row * Dg) : nullptr;
    for (int c0 = tid; c0 < Dg; c0 += 256) {
        float v = (y[c0] - mean) * rstd * g[c0] + bta[c0] + b2f(xir[c0]);
        if (OUTER) v += xo[c0];
        outr[c0] = __float2bfloat16(v);
    }
}

extern "C" void kernel_launch(void* const* d_in, const int* in_sizes, int n_in,
                              void* d_out, int out_size, void* d_ws, size_t ws_size,
                              hipStream_t stream) {
    (void)in_sizes; (void)n_in; (void)out_size; (void)ws_size;
    const int M = MROWS;
    const size_t S_D = (size_t)M * DMODEL;
    const size_t S_H = (size_t)M * DHID;

    const float* x      = (const float*)d_in[0];
    const float* qkv_w  = (const float*)d_in[1];
    const float* qkv_b  = (const float*)d_in[2];
    const float* proj_w = (const float*)d_in[3];
    const float* proj_b = (const float*)d_in[4];
    const float* n1g    = (const float*)d_in[5];
    const float* n1b    = (const float*)d_in[6];
    const float* n2g    = (const float*)d_in[7];
    const float* n2b    = (const float*)d_in[8];
    const float* wa     = (const float*)d_in[9];
    const float* ba     = (const float*)d_in[10];
    const float* sca    = (const float*)d_in[11];
    const float* lga    = (const float*)d_in[12];
    const float* lba    = (const float*)d_in[13];
    const float* wm     = (const float*)d_in[14];
    const float* bm     = (const float*)d_in[15];
    const float* scm    = (const float*)d_in[16];
    const float* lgm    = (const float*)d_in[17];
    const float* lbm    = (const float*)d_in[18];
    const float* f1w    = (const float*)d_in[19];
    const float* f1b    = (const float*)d_in[20];
    const float* f2w    = (const float*)d_in[21];
    const float* f2b    = (const float*)d_in[22];
    const float* eps_a  = (const float*)d_in[23];
    const float* eps_m  = (const float*)d_in[24];

    float* out_x = (float*)d_out;          // M*768 fp32
    float* out_e = out_x + S_D;            // M fp32 (e1+e2)

    // Workspace: bf16 R1[M*3072] | bf16 R2[M*3072] | bf16 R3[M*768] | fp32 E[M]  (~174 MB)
    bf16* R1 = (bf16*)d_ws;
    bf16* R2 = R1 + S_H;
    bf16* R3 = R2 + S_H;
    float* E = (float*)(R3 + S_D);

    const int GY = (M + 127) / 128;   // 99

    // 1. x1 = LN1(x)                     -> R1
    ln_kernel<float><<<M, 256, 0, stream>>>(x, n1g, n1b, R1, DMODEL);
    // 2. qkv = x1 @ qkv_w^T + b          -> R2 (M,2304)
    gemm_mfma<0, bf16><<<dim3(2304 / 128, GY), 256, 0, stream>>>(
        (const short*)R1, qkv_w, qkv_b, nullptr, R2, M, 2304, DMODEL);
    // 3. attention (MFMA)                 -> ctx in R1
    attn_mfma<<<64 * 8, 256, 0, stream>>>(R2, R1);
    // 4. ctxp = ctx @ proj_w^T + b       -> R2
    gemm_mfma<0, bf16><<<dim3(DMODEL / 128, GY), 256, 0, stream>>>(
        (const short*)R1, proj_w, proj_b, nullptr, R2, M, DMODEL, DMODEL);
    // 5. xp_a = ctxp @ wa^T + ba         -> R1
    gemm_mfma<0, bf16><<<dim3(DMODEL / 128, GY), 256, 0, stream>>>(
        (const short*)R2, wa, ba, nullptr, R1, M, DMODEL, DMODEL);
    // 6. adapter-A tail: x_new = x + LN(rot(xp_a)+ctxp)+ctxp -> R3; e1 -> E
    adapter_finish<true, false><<<M, 256, (DMODEL + 80) * sizeof(float), stream>>>(
        R1, R2, x, eps_a, sca, lga, lba, R3, E, nullptr, DMODEL);
    // 7. x2 = LN2(x_new)                 -> R2
    ln_kernel<bf16><<<M, 256, 0, stream>>>(R3, n2g, n2b, R2, DMODEL);
    // 8. h = gelu(x2 @ f1w^T + f1b)      -> R1 (M,3072)
    gemm_mfma<1, bf16><<<dim3(DHID / 128, GY), 256, 0, stream>>>(
        (const short*)R2, f1w, f1b, nullptr, R1, M, DHID, DMODEL);
    // 9. xp_m = h @ wm^T + bm            -> R2 (M,3072)
    gemm_mfma<0, bf16><<<dim3(DHID / 128, GY), 256, 0, stream>>>(
        (const short*)R1, wm, bm, nullptr, R2, M, DHID, DHID);
    // 10. adapter-M tail: h2 = LN(rot(xp_m)+h)+h -> R1 (in place); out_e = E + e2
    adapter_finish<false, true><<<M, 256, (DHID + 80) * sizeof(float), stream>>>(
        R2, R1, nullptr, eps_m, scm, lgm, lbm, R1, E, out_e, DHID);
    // 11. out = x_new + h2 @ f2w^T + f2b -> d_out (fp32)
    gemm_mfma<2, float><<<dim3(DMODEL / 128, GY), 256, 0, stream>>>(
        (const short*)R1, f2w, f2b, R3, out_x, M, DMODEL, DHID);
}

// Round 6
// 1099.623 us; speedup vs baseline: 6.3631x; 1.0813x over previous
//
#include <hip/hip_runtime.h>
#include <hip/hip_bf16.h>
#include <math.h>
#include <type_traits>

// Problem constants (B=64, N=197, D=768, NH=8, HID=3072).
// Global inputs/outputs: fp32 (per reference). Workspace intermediates: bf16.
// GEMMs: bf16 MFMA (16x16x32), 128x128 tile, BK=32, m97-style staging.
// If ws_size permits (~209 MB), weights are pre-converted to bf16 in ws and
// BOTH GEMM operands use global_load_lds width=16 (m97 structure); else the
// B-path falls back to fp32 loads + VALU cvt (round-5 behavior).
#define MROWS (64*197)   // 12608 rows
#define DMODEL 768
#define DHID   3072

typedef __hip_bfloat16 bf16;
using bf16x8 = __attribute__((ext_vector_type(8))) short;  // 8 bf16 (4 VGPRs)
using f32x4  = __attribute__((ext_vector_type(4))) float;  // MFMA accumulator

__device__ __forceinline__ float b2f(bf16 v) { return __bfloat162float(v); }
__device__ __forceinline__ float tof(float v) { return v; }
__device__ __forceinline__ float tof(bf16 v) { return __bfloat162float(v); }
__device__ __forceinline__ short f2bs(float f) {
    bf16 h = __float2bfloat16(f);
    return *reinterpret_cast<short*>(&h);
}
__device__ __forceinline__ float gelu_exact(float v) {
    return 0.5f * v * (1.0f + erff(v * 0.70710678118654752f));
}
__device__ __forceinline__ void st1(bf16* p, float v) { *p = __float2bfloat16(v); }
__device__ __forceinline__ void st1(float* p, float v) { *p = v; }

// async global(16B) -> LDS, gfx950 width-16 variant
__device__ __forceinline__ void gl_lds16(const short* g, short* l) {
    __builtin_amdgcn_global_load_lds(
        (const __attribute__((address_space(1))) void*)g,
        (__attribute__((address_space(3))) void*)l, 16, 0, 0);
}

// ---------------- fp32 -> bf16 weight conversion (elementwise, n%4==0) ----------
__global__ __launch_bounds__(256) void cvt_w_kernel(const float* __restrict__ src,
        short* __restrict__ dst, int n4) {
    int i = blockIdx.x * 256 + threadIdx.x;
    if (i < n4) {
        float4 v = ((const float4*)src)[i];
        short4 h = make_short4(f2bs(v.x), f2bs(v.y), f2bs(v.z), f2bs(v.w));
        ((short4*)dst)[i] = h;
    }
}

// ---------------- LayerNorm (one block per row); in: fp32 or bf16, out: bf16 ----
template<typename TIN>
__global__ __launch_bounds__(256) void ln_kernel(const TIN* __restrict__ in,
        const float* __restrict__ g, const float* __restrict__ b,
        bf16* __restrict__ out, int Dg) {
    int row = blockIdx.x;
    const TIN* xr = in + (size_t)row * Dg;
    bf16* yr = out + (size_t)row * Dg;
    float s = 0.f, s2 = 0.f;
    for (int c = threadIdx.x; c < Dg; c += 256) { float v = tof(xr[c]); s += v; s2 += v * v; }
    __shared__ float r1[4], r2[4];
    for (int off = 32; off; off >>= 1) { s += __shfl_down(s, off, 64); s2 += __shfl_down(s2, off, 64); }
    if ((threadIdx.x & 63) == 0) { r1[threadIdx.x >> 6] = s; r2[threadIdx.x >> 6] = s2; }
    __syncthreads();
    s  = r1[0] + r1[1] + r1[2] + r1[3];
    s2 = r2[0] + r2[1] + r2[2] + r2[3];
    float mean = s / Dg;
    float var  = s2 / Dg - mean * mean;
    float rstd = rsqrtf(var + 1e-5f);
    for (int c = threadIdx.x; c < Dg; c += 256)
        yr[c] = __float2bfloat16((tof(xr[c]) - mean) * rstd * g[c] + b[c]);
}

// ---------------- MFMA GEMM: C[M,N] = A[M,K](bf16) @ W[N,K]^T + bias ------------
// 128x128 tile, BK=32, 4 waves (2x2 of 64x64), 4x4 16x16x32 MFMA per wave.
// A staged via global_load_lds width=16. TB=short: B also global_load_lds (m97).
// TB=float: B staged via float4 loads + VALU cvt + ds_write (fallback).
// MODE 0: +bias   MODE 1: +bias,gelu   MODE 2: +bias,+resid(bf16)
template<int MODE, typename TC, typename TB>
__global__ __launch_bounds__(256) void gemm_mfma(const short* __restrict__ A,
        const TB* __restrict__ W, const float* __restrict__ bias,
        const bf16* __restrict__ resid, TC* __restrict__ C,
        int Mr, int Nc, int Kc)
{
    __shared__ short Abuf[128 * 32];   // [row][k] row-major, 8 KB
    __shared__ short Bbuf[128 * 32];   // [n][k]  row-major, 8 KB
    const int tid  = threadIdx.x;
    const int lane = tid & 63, wave = tid >> 6;
    const int wm = wave & 1, wn = wave >> 1;
    const int quad = lane >> 4, l16 = lane & 15;
    const int m0 = blockIdx.y * 128, n0 = blockIdx.x * 128;

    f32x4 acc[4][4];
#pragma unroll
    for (int i = 0; i < 4; ++i)
#pragma unroll
        for (int j = 0; j < 4; ++j) acc[i][j] = (f32x4){0.f, 0.f, 0.f, 0.f};

    const int brow = tid >> 3;       // 0..31  (row within 32-row sweep, fp32 path)
    const int bk   = (tid & 7) * 4;  // k offset 0..28 (fp32 path)

    for (int k0 = 0; k0 < Kc; k0 += 32) {
        if constexpr (std::is_same<TB, float>::value) {
            // B (weights, fp32): coalesced loads issued before barrier to overlap MFMA
            float4 wv[4];
#pragma unroll
            for (int s = 0; s < 4; ++s)
                wv[s] = *(const float4*)(W + (size_t)(n0 + s * 32 + brow) * Kc + k0 + bk);
            __syncthreads();   // prior tile's MFMA reads done before LDS overwrite
#pragma unroll
            for (int q = 0; q < 2; ++q) {
                int c = q * 256 + tid;
                int rowA = m0 + (c >> 2);
                if (rowA > Mr - 1) rowA = Mr - 1;   // clamp tail tile
                gl_lds16(A + (size_t)rowA * Kc + k0 + (c & 3) * 8, Abuf + c * 8);
            }
#pragma unroll
            for (int s = 0; s < 4; ++s) {
                short4 h;
                h.x = f2bs(wv[s].x); h.y = f2bs(wv[s].y);
                h.z = f2bs(wv[s].z); h.w = f2bs(wv[s].w);
                *(short4*)(Bbuf + (s * 32 + brow) * 32 + bk) = h;
            }
            __syncthreads();   // drains vmcnt (global_load_lds) + lgkm (ds_write)
        } else {
            // m97 structure: both operands async direct-to-LDS, 16B chunks
            __syncthreads();   // prior tile's MFMA reads done before LDS overwrite
#pragma unroll
            for (int q = 0; q < 2; ++q) {
                int c = q * 256 + tid;
                int rowA = m0 + (c >> 2);
                if (rowA > Mr - 1) rowA = Mr - 1;   // clamp tail tile
                gl_lds16(A + (size_t)rowA * Kc + k0 + (c & 3) * 8, Abuf + c * 8);
            }
#pragma unroll
            for (int q = 0; q < 2; ++q) {
                int c = q * 256 + tid;
                gl_lds16((const short*)W + (size_t)(n0 + (c >> 2)) * Kc + k0 + (c & 3) * 8,
                         Bbuf + c * 8);
            }
            __syncthreads();   // drains vmcnt
        }
        // fragments: lane holds [m=l16][k=quad*8..+7]
        bf16x8 fa[4], fb[4];
#pragma unroll
        for (int i = 0; i < 4; ++i)
            fa[i] = *(const bf16x8*)(Abuf + (wm * 64 + i * 16 + l16) * 32 + quad * 8);
#pragma unroll
        for (int j = 0; j < 4; ++j)
            fb[j] = *(const bf16x8*)(Bbuf + (wn * 64 + j * 16 + l16) * 32 + quad * 8);
#pragma unroll
        for (int i = 0; i < 4; ++i)
#pragma unroll
            for (int j = 0; j < 4; ++j)
                acc[i][j] = __builtin_amdgcn_mfma_f32_16x16x32_bf16(fa[i], fb[j], acc[i][j], 0, 0, 0);
    }

    // Epilogue. C/D layout: col = lane&15, row = quad*4 + reg  [m89/m91 verified]
#pragma unroll
    for (int i = 0; i < 4; ++i)
#pragma unroll
        for (int r = 0; r < 4; ++r) {
            int row = m0 + wm * 64 + i * 16 + quad * 4 + r;
            if (row >= Mr) continue;
#pragma unroll
            for (int j = 0; j < 4; ++j) {
                int col = n0 + wn * 64 + j * 16 + l16;
                float v = acc[i][j][r] + bias[col];
                if (MODE == 1) v = gelu_exact(v);
                if (MODE == 2) v += b2f(resid[(size_t)row * Nc + col]);
                st1(C + (size_t)row * Nc + col, v);
            }
        }
}

// ---------------- Attention (MFMA): one block per (b,h) ----------------
// qkv row layout: row (b*197+n), col t*768 + h*96 + d, t in {q,k,v}
__global__ __launch_bounds__(256) void attn_mfma(const bf16* __restrict__ qkv,
        bf16* __restrict__ ctx) {
    const int NS = 197;
    const int KST = 104;   // Kbuf row stride (elems): 2-way bank aliasing only
    const int VST = 232;   // Vt/P row stride (elems): 2-way bank aliasing only
    __shared__ short Kbuf[224 * KST];      // 46.6 KB
    __shared__ short Vt[96 * VST];         // 44.5 KB
    __shared__ short Pbuf[4][16 * VST];    // 29.7 KB (per-wave)
    const int b = blockIdx.x >> 3, h = blockIdx.x & 7;
    const short* base = (const short*)qkv + (size_t)b * NS * 2304 + h * 96;
    const int tid = threadIdx.x;

    for (int c = tid; c < NS * 12; c += 256) {
        int key = c / 12, dc = c % 12;
        bf16x8 v = *(const bf16x8*)(base + (size_t)key * 2304 + 768 + dc * 8);
        *(bf16x8*)(Kbuf + key * KST + dc * 8) = v;
    }
    for (int c = tid; c < 27 * 12; c += 256) {   // zero pad rows 197..223
        int key = NS + c / 12, dc = c % 12;
        *(bf16x8*)(Kbuf + key * KST + dc * 8) = (bf16x8){0, 0, 0, 0, 0, 0, 0, 0};
    }
    for (int c = tid; c < NS * 12; c += 256) {
        int key = c / 12, dc = c % 12;
        bf16x8 v = *(const bf16x8*)(base + (size_t)key * 2304 + 1536 + dc * 8);
#pragma unroll
        for (int j = 0; j < 8; ++j) Vt[(dc * 8 + j) * VST + key] = v[j];
    }
    for (int c = tid; c < 96 * 27; c += 256) {   // zero pad cols 197..223
        int d = c / 27, key = NS + c % 27;
        Vt[d * VST + key] = 0;
    }
    __syncthreads();

    const int wave = tid >> 6, lane = tid & 63;
    const int quad = lane >> 4, l16 = lane & 15;
    short* P = &Pbuf[wave][0];

    for (int qt = wave; qt < 13; qt += 4) {
        int qrow = qt * 16 + l16; if (qrow > NS - 1) qrow = NS - 1;  // clamp tail
        bf16x8 fq[3];
#pragma unroll
        for (int kc = 0; kc < 3; ++kc)
            fq[kc] = *(const bf16x8*)(base + (size_t)qrow * 2304 + kc * 32 + quad * 8);
        f32x4 s[14];
#pragma unroll
        for (int nt = 0; nt < 14; ++nt) {
            s[nt] = (f32x4){0.f, 0.f, 0.f, 0.f};
#pragma unroll
            for (int kc = 0; kc < 3; ++kc) {
                bf16x8 fk = *(const bf16x8*)(Kbuf + (nt * 16 + l16) * KST + kc * 32 + quad * 8);
                s[nt] = __builtin_amdgcn_mfma_f32_16x16x32_bf16(fq[kc], fk, s[nt], 0, 0, 0);
            }
        }
        const float sc = 0.10206207261596577f;   // 96^-0.5
        float mx[4] = {-1e30f, -1e30f, -1e30f, -1e30f};
#pragma unroll
        for (int nt = 0; nt < 14; ++nt) {
            bool valid = nt * 16 + l16 < NS;
#pragma unroll
            for (int r = 0; r < 4; ++r) {
                float v = s[nt][r] * sc;
                s[nt][r] = v;
                if (valid) mx[r] = fmaxf(mx[r], v);
            }
        }
#pragma unroll
        for (int m = 1; m < 16; m <<= 1)
#pragma unroll
            for (int r = 0; r < 4; ++r) mx[r] = fmaxf(mx[r], __shfl_xor(mx[r], m, 64));
        float l[4] = {0.f, 0.f, 0.f, 0.f};
#pragma unroll
        for (int nt = 0; nt < 14; ++nt) {
            bool valid = nt * 16 + l16 < NS;
#pragma unroll
            for (int r = 0; r < 4; ++r) {
                float e = valid ? __expf(s[nt][r] - mx[r]) : 0.f;
                l[r] += e;
                P[(quad * 4 + r) * VST + nt * 16 + l16] = f2bs(e);
            }
        }
#pragma unroll
        for (int m = 1; m < 16; m <<= 1)
#pragma unroll
            for (int r = 0; r < 4; ++r) l[r] += __shfl_xor(l[r], m, 64);
        __asm__ volatile("s_waitcnt lgkmcnt(0)" ::: "memory");
        f32x4 o[6];
#pragma unroll
        for (int nt = 0; nt < 6; ++nt) o[nt] = (f32x4){0.f, 0.f, 0.f, 0.f};
#pragma unroll
        for (int kc = 0; kc < 7; ++kc) {
            bf16x8 fp = *(const bf16x8*)(P + l16 * VST + kc * 32 + quad * 8);
#pragma unroll
            for (int nt = 0; nt < 6; ++nt) {
                bf16x8 fv = *(const bf16x8*)(Vt + (nt * 16 + l16) * VST + kc * 32 + quad * 8);
                o[nt] = __builtin_amdgcn_mfma_f32_16x16x32_bf16(fp, fv, o[nt], 0, 0, 0);
            }
        }
        float inv[4];
#pragma unroll
        for (int r = 0; r < 4; ++r) inv[r] = 1.f / l[r];
#pragma unroll
        for (int r = 0; r < 4; ++r) {
            int q = qt * 16 + quad * 4 + r;
            if (q >= NS) continue;
            bf16* orow = ctx + ((size_t)(b * NS + q)) * 768 + h * 96;
#pragma unroll
            for (int nt = 0; nt < 6; ++nt)
                orow[nt * 16 + l16] = __float2bfloat16(o[nt][r] * inv[r]);
        }
    }
}

// ---------------- SO(8) adapter tail: rotate + err + LN + residuals ----------------
template<bool OUTER, bool FINAL>
__global__ __launch_bounds__(256) void adapter_finish(
        const bf16* __restrict__ xp, const bf16* __restrict__ xin,
        const float* __restrict__ xouter, const float* __restrict__ eps,
        const float* __restrict__ scale_p, const float* __restrict__ g,
        const float* __restrict__ bta, bf16* __restrict__ out,
        float* __restrict__ e_acc, float* __restrict__ e_out, int Dg)
{
    extern __shared__ float smem[];
    float* y = smem;            // Dg
    float* diff2 = smem + Dg;   // 64
    float* red = diff2 + 64;    // 8 head-norms
    float* r1 = red + 8;        // 4
    float* r2 = red + 12;       // 4
    int row = blockIdx.x;
    int hd = Dg >> 3;           // 96 or 384
    const bf16* xpr = xp + (size_t)row * Dg;
    const bf16* xir = xin + (size_t)row * Dg;
    int tid = threadIdx.x;
    if (tid < 64) {
        int hh = tid >> 3, i = tid & 7, p = i >> 1;
        float ang = eps[((size_t)row * 8 + hh) * 4 + p] * scale_p[0];
        float c = cosf(ang), sn = sinf(ang);
        int base = hh * hd;
        float ev = b2f(xpr[base + 2 * p]), od = b2f(xpr[base + 2 * p + 1]);
        float r = (i & 1) ? (ev * sn + od * c) : (ev * c - od * sn);
        float d = r - b2f(xpr[base + i]);
        diff2[tid] = d * d;
        y[base + i] = r + b2f(xir[base + i]);
    }
    for (int c0 = tid; c0 < Dg; c0 += 256) {
        if ((c0 % hd) >= 8) y[c0] = b2f(xpr[c0]) + b2f(xir[c0]);
    }
    __syncthreads();
    if (tid < 8) {
        float t = 0.f;
#pragma unroll
        for (int i = 0; i < 8; ++i) t += diff2[tid * 8 + i];
        red[tid] = sqrtf(t);
    }
    float s = 0.f, s2 = 0.f;
    for (int c0 = tid; c0 < Dg; c0 += 256) { float v = y[c0]; s += v; s2 += v * v; }
    for (int off = 32; off; off >>= 1) { s += __shfl_down(s, off, 64); s2 += __shfl_down(s2, off, 64); }
    if ((tid & 63) == 0) { r1[tid >> 6] = s; r2[tid >> 6] = s2; }
    __syncthreads();
    s  = r1[0] + r1[1] + r1[2] + r1[3];
    s2 = r2[0] + r2[1] + r2[2] + r2[3];
    float mean = s / Dg;
    float var  = s2 / Dg - mean * mean;
    float rstd = rsqrtf(var + 1e-5f);
    if (tid == 0) {
        float e = (red[0] + red[1] + red[2] + red[3] + red[4] + red[5] + red[6] + red[7]) * 0.125f;
        if (FINAL) e_out[row] = e_acc[row] + e;
        else       e_acc[row] = e;
    }
    bf16* outr = out + (size_t)row * Dg;
    const float* xo = OUTER ? (xouter + (size_t)row * Dg) : nullptr;
    for (int c0 = tid; c0 < Dg; c0 += 256) {
        float v = (y[c0] - mean) * rstd * g[c0] + bta[c0] + b2f(xir[c0]);
        if (OUTER) v += xo[c0];
        outr[c0] = __float2bfloat16(v);
    }
}

extern "C" void kernel_launch(void* const* d_in, const int* in_sizes, int n_in,
                              void* d_out, int out_size, void* d_ws, size_t ws_size,
                              hipStream_t stream) {
    (void)in_sizes; (void)n_in; (void)out_size;
    const int M = MROWS;
    const size_t S_D = (size_t)M * DMODEL;
    const size_t S_H = (size_t)M * DHID;

    const float* x      = (const float*)d_in[0];
    const float* qkv_w  = (const float*)d_in[1];
    const float* qkv_b  = (const float*)d_in[2];
    const float* proj_w = (const float*)d_in[3];
    const float* proj_b = (const float*)d_in[4];
    const float* n1g    = (const float*)d_in[5];
    const float* n1b    = (const float*)d_in[6];
    const float* n2g    = (const float*)d_in[7];
    const float* n2b    = (const float*)d_in[8];
    const float* wa     = (const float*)d_in[9];
    const float* ba     = (const float*)d_in[10];
    const float* sca    = (const float*)d_in[11];
    const float* lga    = (const float*)d_in[12];
    const float* lba    = (const float*)d_in[13];
    const float* wm     = (const float*)d_in[14];
    const float* bm     = (const float*)d_in[15];
    const float* scm    = (const float*)d_in[16];
    const float* lgm    = (const float*)d_in[17];
    const float* lbm    = (const float*)d_in[18];
    const float* f1w    = (const float*)d_in[19];
    const float* f1b    = (const float*)d_in[20];
    const float* f2w    = (const float*)d_in[21];
    const float* f2b    = (const float*)d_in[22];
    const float* eps_a  = (const float*)d_in[23];
    const float* eps_m  = (const float*)d_in[24];

    float* out_x = (float*)d_out;          // M*768 fp32
    float* out_e = out_x + S_D;            // M fp32 (e1+e2)

    // Workspace: bf16 R1[M*3072] | bf16 R2[M*3072] | bf16 R3[M*768] | fp32 E[M]
    // | (optional) bf16 weight cache (~34.2 MB)
    bf16* R1 = (bf16*)d_ws;
    bf16* R2 = R1 + S_H;
    bf16* R3 = R2 + S_H;
    float* E = (float*)(R3 + S_D);

    const size_t n_qkv = (size_t)2304 * 768, n_proj = (size_t)768 * 768,
                 n_wa = (size_t)768 * 768, n_wm = (size_t)3072 * 3072,
                 n_f1 = (size_t)3072 * 768, n_f2 = (size_t)768 * 3072;
    const size_t base_bytes = (2 * S_H + S_D) * 2 + (size_t)M * 4;
    const size_t w_elems = n_qkv + n_proj + n_wa + n_wm + n_f1 + n_f2;
    const bool cache_w = ws_size >= base_bytes + w_elems * 2;

    short* WB    = (short*)((char*)d_ws + base_bytes);
    short* wb_qkv = WB;
    short* wb_proj = wb_qkv + n_qkv;
    short* wb_wa  = wb_proj + n_proj;
    short* wb_wm  = wb_wa + n_wa;
    short* wb_f1  = wb_wm + n_wm;
    short* wb_f2  = wb_f1 + n_f1;

    const int GY = (M + 127) / 128;   // 99

    if (cache_w) {
        cvt_w_kernel<<<(int)(n_qkv / 4 + 255) / 256, 256, 0, stream>>>(qkv_w, wb_qkv, (int)(n_qkv / 4));
        cvt_w_kernel<<<(int)(n_proj / 4 + 255) / 256, 256, 0, stream>>>(proj_w, wb_proj, (int)(n_proj / 4));
        cvt_w_kernel<<<(int)(n_wa / 4 + 255) / 256, 256, 0, stream>>>(wa, wb_wa, (int)(n_wa / 4));
        cvt_w_kernel<<<(int)(n_wm / 4 + 255) / 256, 256, 0, stream>>>(wm, wb_wm, (int)(n_wm / 4));
        cvt_w_kernel<<<(int)(n_f1 / 4 + 255) / 256, 256, 0, stream>>>(f1w, wb_f1, (int)(n_f1 / 4));
        cvt_w_kernel<<<(int)(n_f2 / 4 + 255) / 256, 256, 0, stream>>>(f2w, wb_f2, (int)(n_f2 / 4));
    }

    // 1. x1 = LN1(x)                     -> R1
    ln_kernel<float><<<M, 256, 0, stream>>>(x, n1g, n1b, R1, DMODEL);
    if (cache_w) {
        // 2. qkv = x1 @ qkv_w^T + b      -> R2 (M,2304)
        gemm_mfma<0, bf16, short><<<dim3(2304 / 128, GY), 256, 0, stream>>>(
            (const short*)R1, wb_qkv, qkv_b, nullptr, R2, M, 2304, DMODEL);
        attn_mfma<<<64 * 8, 256, 0, stream>>>(R2, R1);
        gemm_mfma<0, bf16, short><<<dim3(DMODEL / 128, GY), 256, 0, stream>>>(
            (const short*)R1, wb_proj, proj_b, nullptr, R2, M, DMODEL, DMODEL);
        gemm_mfma<0, bf16, short><<<dim3(DMODEL / 128, GY), 256, 0, stream>>>(
            (const short*)R2, wb_wa, ba, nullptr, R1, M, DMODEL, DMODEL);
        adapter_finish<true, false><<<M, 256, (DMODEL + 80) * sizeof(float), stream>>>(
            R1, R2, x, eps_a, sca, lga, lba, R3, E, nullptr, DMODEL);
        ln_kernel<bf16><<<M, 256, 0, stream>>>(R3, n2g, n2b, R2, DMODEL);
        gemm_mfma<1, bf16, short><<<dim3(DHID / 128, GY), 256, 0, stream>>>(
            (const short*)R2, wb_f1, f1b, nullptr, R1, M, DHID, DMODEL);
        gemm_mfma<0, bf16, short><<<dim3(DHID / 128, GY), 256, 0, stream>>>(
            (const short*)R1, wb_wm, bm, nullptr, R2, M, DHID, DHID);
        adapter_finish<false, true><<<M, 256, (DHID + 80) * sizeof(float), stream>>>(
            R2, R1, nullptr, eps_m, scm, lgm, lbm, R1, E, out_e, DHID);
        gemm_mfma<2, float, short><<<dim3(DMODEL / 128, GY), 256, 0, stream>>>(
            (const short*)R1, wb_f2, f2b, R3, out_x, M, DMODEL, DHID);
    } else {
        // Fallback: fp32 weight staging (round-5 behavior)
        gemm_mfma<0, bf16, float><<<dim3(2304 / 128, GY), 256, 0, stream>>>(
            (const short*)R1, qkv_w, qkv_b, nullptr, R2, M, 2304, DMODEL);
        attn_mfma<<<64 * 8, 256, 0, stream>>>(R2, R1);
        gemm_mfma<0, bf16, float><<<dim3(DMODEL / 128, GY), 256, 0, stream>>>(
            (const short*)R1, proj_w, proj_b, nullptr, R2, M, DMODEL, DMODEL);
        gemm_mfma<0, bf16, float><<<dim3(DMODEL / 128, GY), 256, 0, stream>>>(
            (const short*)R2, wa, ba, nullptr, R1, M, DMODEL, DMODEL);
        adapter_finish<true, false><<<M, 256, (DMODEL + 80) * sizeof(float), stream>>>(
            R1, R2, x, eps_a, sca, lga, lba, R3, E, nullptr, DMODEL);
        ln_kernel<bf16><<<M, 256, 0, stream>>>(R3, n2g, n2b, R2, DMODEL);
        gemm_mfma<1, bf16, float><<<dim3(DHID / 128, GY), 256, 0, stream>>>(
            (const short*)R2, f1w, f1b, nullptr, R1, M, DHID, DMODEL);
        gemm_mfma<0, bf16, float><<<dim3(DHID / 128, GY), 256, 0, stream>>>(
            (const short*)R1, wm, bm, nullptr, R2, M, DHID, DHID);
        adapter_finish<false, true><<<M, 256, (DHID + 80) * sizeof(float), stream>>>(
            R2, R1, nullptr, eps_m, scm, lgm, lbm, R1, E, out_e, DHID);
        gemm_mfma<2, float, float><<<dim3(DMODEL / 128, GY), 256, 0, stream>>>(
            (const short*)R1, f2w, f2b, R3, out_x, M, DMODEL, DHID);
    }
}

// Round 7
// 911.180 us; speedup vs baseline: 7.6790x; 1.2068x over previous
//
#include <hip/hip_runtime.h>
#include <hip/hip_bf16.h>
#include <math.h>

// Problem constants (B=64, N=197, D=768, NH=8, HID=3072).
// fp32 global I/O; bf16 ws intermediates; bf16 weight cache in ws when it fits.
// GEMM: 16x16x32 MFMA, 128x128 tile, BK=64, both operands global_load_lds w=16,
// XOR-swizzled LDS chunk map (2-way bank aliasing on ds_read_b128).
#define MROWS (64*197)   // 12608 rows
#define DMODEL 768
#define DHID   3072

typedef __hip_bfloat16 bf16;
using bf16x8 = __attribute__((ext_vector_type(8))) short;  // 8 bf16 (4 VGPRs)
using f32x4  = __attribute__((ext_vector_type(4))) float;  // MFMA accumulator

__device__ __forceinline__ float b2f(bf16 v) { return __bfloat162float(v); }
__device__ __forceinline__ short f2bs(float f) {
    bf16 h = __float2bfloat16(f);
    return *reinterpret_cast<short*>(&h);
}
__device__ __forceinline__ void b8f(bf16x8 v, float* f) {
#pragma unroll
    for (int j = 0; j < 8; ++j)
        f[j] = __uint_as_float(((unsigned int)(unsigned short)v[j]) << 16);
}
__device__ __forceinline__ bf16x8 f8b(const float* f) {
    bf16x8 r;
#pragma unroll
    for (int j = 0; j < 8; ++j) r[j] = f2bs(f[j]);
    return r;
}
__device__ __forceinline__ float gelu_exact(float v) {
    return 0.5f * v * (1.0f + erff(v * 0.70710678118654752f));
}
__device__ __forceinline__ void st1(bf16* p, float v) { *p = __float2bfloat16(v); }
__device__ __forceinline__ void st1(float* p, float v) { *p = v; }

// async global(16B) -> LDS, gfx950 width-16 variant
__device__ __forceinline__ void gl_lds16(const short* g, short* l) {
    __builtin_amdgcn_global_load_lds(
        (const __attribute__((address_space(1))) void*)g,
        (__attribute__((address_space(3))) void*)l, 16, 0, 0);
}

// ---------------- merged fp32 -> bf16 weight conversion (single launch) --------
// dst is one contiguous bf16 cache; segments in fixed order (float4 units).
__global__ __launch_bounds__(256) void cvt_all_kernel(
        const float* __restrict__ s0, const float* __restrict__ s1,
        const float* __restrict__ s2, const float* __restrict__ s3,
        const float* __restrict__ s4, const float* __restrict__ s5,
        short* __restrict__ dst) {
    const int b0 = 442368, b1 = 589824, b2 = 737280,
              b3 = 3096576, b4 = 3686400, b5 = 4276224;
    int i = blockIdx.x * 256 + threadIdx.x;
    if (i >= b5) return;
    const float* src; int off;
    if      (i < b0) { src = s0; off = i; }
    else if (i < b1) { src = s1; off = i - b0; }
    else if (i < b2) { src = s2; off = i - b1; }
    else if (i < b3) { src = s3; off = i - b2; }
    else if (i < b4) { src = s4; off = i - b3; }
    else             { src = s5; off = i - b4; }
    float4 v = ((const float4*)src)[off];
    ((short4*)dst)[i] = make_short4(f2bs(v.x), f2bs(v.y), f2bs(v.z), f2bs(v.w));
}

// ---------------- LN1 (fp32 in, bf16 out), vectorized x4 ----------------
__global__ __launch_bounds__(256) void ln1_kernel(const float* __restrict__ in,
        const float* __restrict__ g, const float* __restrict__ b,
        bf16* __restrict__ out, int Dg) {
    int row = blockIdx.x;
    int n4 = Dg >> 2;
    const float4* xr = (const float4*)(in + (size_t)row * Dg);
    float s = 0.f, s2 = 0.f;
    for (int c = threadIdx.x; c < n4; c += 256) {
        float4 v = xr[c];
        s += v.x + v.y + v.z + v.w;
        s2 += v.x * v.x + v.y * v.y + v.z * v.z + v.w * v.w;
    }
    __shared__ float r1[4], r2[4];
    for (int off = 32; off; off >>= 1) { s += __shfl_down(s, off, 64); s2 += __shfl_down(s2, off, 64); }
    if ((threadIdx.x & 63) == 0) { r1[threadIdx.x >> 6] = s; r2[threadIdx.x >> 6] = s2; }
    __syncthreads();
    s  = r1[0] + r1[1] + r1[2] + r1[3];
    s2 = r2[0] + r2[1] + r2[2] + r2[3];
    float mean = s / Dg;
    float rstd = rsqrtf(s2 / Dg - mean * mean + 1e-5f);
    short4* yr = (short4*)(out + (size_t)row * Dg);
    const float4* g4 = (const float4*)g;
    const float4* b4 = (const float4*)b;
    for (int c = threadIdx.x; c < n4; c += 256) {
        float4 v = xr[c], gg = g4[c], bb = b4[c];
        yr[c] = make_short4(f2bs((v.x - mean) * rstd * gg.x + bb.x),
                            f2bs((v.y - mean) * rstd * gg.y + bb.y),
                            f2bs((v.z - mean) * rstd * gg.z + bb.z),
                            f2bs((v.w - mean) * rstd * gg.w + bb.w));
    }
}

// ---------------- MFMA GEMM (bf16 x bf16): BK=64, XOR-swizzled LDS --------------
// LDS slot map: slot(row,kc) = row*8 + (kc ^ (row&7)); chunk = 8 bf16 = 16 B.
// Write side is lane-linear (global_load_lds constraint); swizzle is applied by
// permuting the global source k-chunk. Read side ds_read_b128 spans all 32 banks
// (2-way aliasing only). MODE 0:+bias 1:+bias,gelu 2:+bias,+resid(bf16)
template<int MODE, typename TC>
__global__ __launch_bounds__(256) void gemm_bf(const short* __restrict__ A,
        const short* __restrict__ W, const float* __restrict__ bias,
        const bf16* __restrict__ resid, TC* __restrict__ C,
        int Mr, int Nc, int Kc)
{
    __shared__ short Abuf[128 * 64];   // 16 KB
    __shared__ short Bbuf[128 * 64];   // 16 KB
    const int tid  = threadIdx.x;
    const int lane = tid & 63, wave = tid >> 6;
    const int wm = wave & 1, wn = wave >> 1;
    const int quad = lane >> 4, l16 = lane & 15;
    const int m0 = blockIdx.y * 128, n0 = blockIdx.x * 128;

    f32x4 acc[4][4];
#pragma unroll
    for (int i = 0; i < 4; ++i)
#pragma unroll
        for (int j = 0; j < 4; ++j) acc[i][j] = (f32x4){0.f, 0.f, 0.f, 0.f};

    for (int k0 = 0; k0 < Kc; k0 += 64) {
        __syncthreads();   // prior slab's ds_reads done before LDS overwrite
#pragma unroll
        for (int q = 0; q < 4; ++q) {
            int c = q * 256 + tid;
            int row = c >> 3;
            int j = (c & 7) ^ (row & 7);      // global k-chunk for this LDS slot
            int rowA = m0 + row;
            if (rowA > Mr - 1) rowA = Mr - 1; // clamp tail tile (discarded at store)
            gl_lds16(A + (size_t)rowA * Kc + k0 + j * 8, Abuf + c * 8);
        }
#pragma unroll
        for (int q = 0; q < 4; ++q) {
            int c = q * 256 + tid;
            int row = c >> 3;
            int j = (c & 7) ^ (row & 7);
            gl_lds16(W + (size_t)(n0 + row) * Kc + k0 + j * 8, Bbuf + c * 8);
        }
        __syncthreads();   // drains vmcnt (global_load_lds)
#pragma unroll
        for (int t = 0; t < 2; ++t) {
            bf16x8 fa[4], fb[4];
#pragma unroll
            for (int i = 0; i < 4; ++i) {
                int r = wm * 64 + i * 16 + l16;
                fa[i] = *(const bf16x8*)(Abuf + r * 64 + (((t * 4 + quad) ^ (r & 7)) << 3));
            }
#pragma unroll
            for (int j = 0; j < 4; ++j) {
                int r = wn * 64 + j * 16 + l16;
                fb[j] = *(const bf16x8*)(Bbuf + r * 64 + (((t * 4 + quad) ^ (r & 7)) << 3));
            }
#pragma unroll
            for (int i = 0; i < 4; ++i)
#pragma unroll
                for (int j = 0; j < 4; ++j)
                    acc[i][j] = __builtin_amdgcn_mfma_f32_16x16x32_bf16(fa[i], fb[j], acc[i][j], 0, 0, 0);
        }
    }

    // Epilogue. C/D layout: col = lane&15, row = quad*4 + reg  [m89/m91 verified]
#pragma unroll
    for (int i = 0; i < 4; ++i)
#pragma unroll
        for (int r = 0; r < 4; ++r) {
            int row = m0 + wm * 64 + i * 16 + quad * 4 + r;
            if (row >= Mr) continue;
#pragma unroll
            for (int j = 0; j < 4; ++j) {
                int col = n0 + wn * 64 + j * 16 + l16;
                float v = acc[i][j][r] + bias[col];
                if (MODE == 1) v = gelu_exact(v);
                if (MODE == 2) v += b2f(resid[(size_t)row * Nc + col]);
                st1(C + (size_t)row * Nc + col, v);
            }
        }
}

// ---------------- fallback GEMM (fp32 weights, BK=32, round-6 proven) -----------
template<int MODE, typename TC>
__global__ __launch_bounds__(256) void gemm_f32b(const short* __restrict__ A,
        const float* __restrict__ W, const float* __restrict__ bias,
        const bf16* __restrict__ resid, TC* __restrict__ C,
        int Mr, int Nc, int Kc)
{
    __shared__ short Abuf[128 * 32];
    __shared__ short Bbuf[128 * 32];
    const int tid  = threadIdx.x;
    const int lane = tid & 63, wave = tid >> 6;
    const int wm = wave & 1, wn = wave >> 1;
    const int quad = lane >> 4, l16 = lane & 15;
    const int m0 = blockIdx.y * 128, n0 = blockIdx.x * 128;
    f32x4 acc[4][4];
#pragma unroll
    for (int i = 0; i < 4; ++i)
#pragma unroll
        for (int j = 0; j < 4; ++j) acc[i][j] = (f32x4){0.f, 0.f, 0.f, 0.f};
    const int brow = tid >> 3;
    const int bk   = (tid & 7) * 4;
    for (int k0 = 0; k0 < Kc; k0 += 32) {
        float4 wv[4];
#pragma unroll
        for (int s = 0; s < 4; ++s)
            wv[s] = *(const float4*)(W + (size_t)(n0 + s * 32 + brow) * Kc + k0 + bk);
        __syncthreads();
#pragma unroll
        for (int q = 0; q < 2; ++q) {
            int c = q * 256 + tid;
            int rowA = m0 + (c >> 2);
            if (rowA > Mr - 1) rowA = Mr - 1;
            gl_lds16(A + (size_t)rowA * Kc + k0 + (c & 3) * 8, Abuf + c * 8);
        }
#pragma unroll
        for (int s = 0; s < 4; ++s) {
            short4 h = make_short4(f2bs(wv[s].x), f2bs(wv[s].y), f2bs(wv[s].z), f2bs(wv[s].w));
            *(short4*)(Bbuf + (s * 32 + brow) * 32 + bk) = h;
        }
        __syncthreads();
        bf16x8 fa[4], fb[4];
#pragma unroll
        for (int i = 0; i < 4; ++i)
            fa[i] = *(const bf16x8*)(Abuf + (wm * 64 + i * 16 + l16) * 32 + quad * 8);
#pragma unroll
        for (int j = 0; j < 4; ++j)
            fb[j] = *(const bf16x8*)(Bbuf + (wn * 64 + j * 16 + l16) * 32 + quad * 8);
#pragma unroll
        for (int i = 0; i < 4; ++i)
#pragma unroll
            for (int j = 0; j < 4; ++j)
                acc[i][j] = __builtin_amdgcn_mfma_f32_16x16x32_bf16(fa[i], fb[j], acc[i][j], 0, 0, 0);
    }
#pragma unroll
    for (int i = 0; i < 4; ++i)
#pragma unroll
        for (int r = 0; r < 4; ++r) {
            int row = m0 + wm * 64 + i * 16 + quad * 4 + r;
            if (row >= Mr) continue;
#pragma unroll
            for (int j = 0; j < 4; ++j) {
                int col = n0 + wn * 64 + j * 16 + l16;
                float v = acc[i][j][r] + bias[col];
                if (MODE == 1) v = gelu_exact(v);
                if (MODE == 2) v += b2f(resid[(size_t)row * Nc + col]);
                st1(C + (size_t)row * Nc + col, v);
            }
        }
}

// ---------------- Attention (MFMA): one block per (b,h) ----------------
__global__ __launch_bounds__(256) void attn_mfma(const bf16* __restrict__ qkv,
        bf16* __restrict__ ctx) {
    const int NS = 197;
    const int KST = 104;
    const int VST = 232;
    __shared__ short Kbuf[224 * KST];
    __shared__ short Vt[96 * VST];
    __shared__ short Pbuf[4][16 * VST];
    const int b = blockIdx.x >> 3, h = blockIdx.x & 7;
    const short* base = (const short*)qkv + (size_t)b * NS * 2304 + h * 96;
    const int tid = threadIdx.x;

    for (int c = tid; c < NS * 12; c += 256) {
        int key = c / 12, dc = c % 12;
        bf16x8 v = *(const bf16x8*)(base + (size_t)key * 2304 + 768 + dc * 8);
        *(bf16x8*)(Kbuf + key * KST + dc * 8) = v;
    }
    for (int c = tid; c < 27 * 12; c += 256) {
        int key = NS + c / 12, dc = c % 12;
        *(bf16x8*)(Kbuf + key * KST + dc * 8) = (bf16x8){0, 0, 0, 0, 0, 0, 0, 0};
    }
    for (int c = tid; c < NS * 12; c += 256) {
        int key = c / 12, dc = c % 12;
        bf16x8 v = *(const bf16x8*)(base + (size_t)key * 2304 + 1536 + dc * 8);
#pragma unroll
        for (int j = 0; j < 8; ++j) Vt[(dc * 8 + j) * VST + key] = v[j];
    }
    for (int c = tid; c < 96 * 27; c += 256) {
        int d = c / 27, key = NS + c % 27;
        Vt[d * VST + key] = 0;
    }
    __syncthreads();

    const int wave = tid >> 6, lane = tid & 63;
    const int quad = lane >> 4, l16 = lane & 15;
    short* P = &Pbuf[wave][0];

    for (int qt = wave; qt < 13; qt += 4) {
        int qrow = qt * 16 + l16; if (qrow > NS - 1) qrow = NS - 1;
        bf16x8 fq[3];
#pragma unroll
        for (int kc = 0; kc < 3; ++kc)
            fq[kc] = *(const bf16x8*)(base + (size_t)qrow * 2304 + kc * 32 + quad * 8);
        f32x4 s[14];
#pragma unroll
        for (int nt = 0; nt < 14; ++nt) {
            s[nt] = (f32x4){0.f, 0.f, 0.f, 0.f};
#pragma unroll
            for (int kc = 0; kc < 3; ++kc) {
                bf16x8 fk = *(const bf16x8*)(Kbuf + (nt * 16 + l16) * KST + kc * 32 + quad * 8);
                s[nt] = __builtin_amdgcn_mfma_f32_16x16x32_bf16(fq[kc], fk, s[nt], 0, 0, 0);
            }
        }
        const float sc = 0.10206207261596577f;
        float mx[4] = {-1e30f, -1e30f, -1e30f, -1e30f};
#pragma unroll
        for (int nt = 0; nt < 14; ++nt) {
            bool valid = nt * 16 + l16 < NS;
#pragma unroll
            for (int r = 0; r < 4; ++r) {
                float v = s[nt][r] * sc;
                s[nt][r] = v;
                if (valid) mx[r] = fmaxf(mx[r], v);
            }
        }
#pragma unroll
        for (int m = 1; m < 16; m <<= 1)
#pragma unroll
            for (int r = 0; r < 4; ++r) mx[r] = fmaxf(mx[r], __shfl_xor(mx[r], m, 64));
        float l[4] = {0.f, 0.f, 0.f, 0.f};
#pragma unroll
        for (int nt = 0; nt < 14; ++nt) {
            bool valid = nt * 16 + l16 < NS;
#pragma unroll
            for (int r = 0; r < 4; ++r) {
                float e = valid ? __expf(s[nt][r] - mx[r]) : 0.f;
                l[r] += e;
                P[(quad * 4 + r) * VST + nt * 16 + l16] = f2bs(e);
            }
        }
#pragma unroll
        for (int m = 1; m < 16; m <<= 1)
#pragma unroll
            for (int r = 0; r < 4; ++r) l[r] += __shfl_xor(l[r], m, 64);
        __asm__ volatile("s_waitcnt lgkmcnt(0)" ::: "memory");
        f32x4 o[6];
#pragma unroll
        for (int nt = 0; nt < 6; ++nt) o[nt] = (f32x4){0.f, 0.f, 0.f, 0.f};
#pragma unroll
        for (int kc = 0; kc < 7; ++kc) {
            bf16x8 fp = *(const bf16x8*)(P + l16 * VST + kc * 32 + quad * 8);
#pragma unroll
            for (int nt = 0; nt < 6; ++nt) {
                bf16x8 fv = *(const bf16x8*)(Vt + (nt * 16 + l16) * VST + kc * 32 + quad * 8);
                o[nt] = __builtin_amdgcn_mfma_f32_16x16x32_bf16(fp, fv, o[nt], 0, 0, 0);
            }
        }
        float inv[4];
#pragma unroll
        for (int r = 0; r < 4; ++r) inv[r] = 1.f / l[r];
#pragma unroll
        for (int r = 0; r < 4; ++r) {
            int q = qt * 16 + quad * 4 + r;
            if (q >= NS) continue;
            bf16* orow = ctx + ((size_t)(b * NS + q)) * 768 + h * 96;
#pragma unroll
            for (int nt = 0; nt < 6; ++nt)
                orow[nt * 16 + l16] = __float2bfloat16(o[nt][r] * inv[r]);
        }
    }
}

// ---------------- SO(8) adapter tail: rotate + err + LN + residuals -------------
// y = rot(xp)+xin; out = LN(y)*g+bta+xin (+xouter if OUTER)
// FLN2: additionally out2 = LN2(out)*g2+b2 (second in-block reduction).
// FINAL: e_out[row] = e_acc[row]+e else e_acc[row]=e.
// Vectorized bf16x8 global access. Dynamic LDS: (Dg+96) floats.
template<bool OUTER, bool FINAL, bool FLN2>
__global__ __launch_bounds__(256) void adapter_finish(
        const bf16* __restrict__ xp, const bf16* __restrict__ xin,
        const float* __restrict__ xouter, const float* __restrict__ eps,
        const float* __restrict__ scale_p, const float* __restrict__ g,
        const float* __restrict__ bta, bf16* __restrict__ out,
        float* __restrict__ e_acc, float* __restrict__ e_out,
        const float* __restrict__ g2, const float* __restrict__ b2,
        bf16* __restrict__ out2, int Dg)
{
    extern __shared__ float smem[];
    float* y = smem;            // Dg
    float* diff2 = smem + Dg;   // 64
    float* red = diff2 + 64;    // 8 head-norms
    float* r1 = red + 8;        // 4
    float* r2 = red + 12;       // 4
    int row = blockIdx.x;
    int hd = Dg >> 3;           // 96 or 384
    int hd8 = hd >> 3;          // chunks per head
    int n8 = Dg >> 3;
    const bf16* xpr = xp + (size_t)row * Dg;
    const bf16* xir = xin + (size_t)row * Dg;
    int tid = threadIdx.x;
    if (tid < 64) {
        int hh = tid >> 3, i = tid & 7, p = i >> 1;
        float ang = eps[((size_t)row * 8 + hh) * 4 + p] * scale_p[0];
        float c = cosf(ang), sn = sinf(ang);
        int base = hh * hd;
        float ev = b2f(xpr[base + 2 * p]), od = b2f(xpr[base + 2 * p + 1]);
        float r = (i & 1) ? (ev * sn + od * c) : (ev * c - od * sn);
        float d = r - b2f(xpr[base + i]);
        diff2[tid] = d * d;
        y[base + i] = r + b2f(xir[base + i]);
    }
    for (int c8 = tid; c8 < n8; c8 += 256) {
        if (c8 % hd8 == 0) continue;   // rot chunk: handled above
        float a[8], bvx[8];
        b8f(*(const bf16x8*)(xpr + c8 * 8), a);
        b8f(*(const bf16x8*)(xir + c8 * 8), bvx);
#pragma unroll
        for (int j = 0; j < 8; ++j) y[c8 * 8 + j] = a[j] + bvx[j];
    }
    __syncthreads();
    if (tid < 8) {
        float t = 0.f;
#pragma unroll
        for (int i = 0; i < 8; ++i) t += diff2[tid * 8 + i];
        red[tid] = sqrtf(t);
    }
    float s = 0.f, s2 = 0.f;
    for (int c = tid; c < Dg; c += 256) { float v = y[c]; s += v; s2 += v * v; }
    for (int off = 32; off; off >>= 1) { s += __shfl_down(s, off, 64); s2 += __shfl_down(s2, off, 64); }
    if ((tid & 63) == 0) { r1[tid >> 6] = s; r2[tid >> 6] = s2; }
    __syncthreads();
    s  = r1[0] + r1[1] + r1[2] + r1[3];
    s2 = r2[0] + r2[1] + r2[2] + r2[3];
    float mean = s / Dg;
    float rstd = rsqrtf(s2 / Dg - mean * mean + 1e-5f);
    if (tid == 0) {
        float e = (red[0] + red[1] + red[2] + red[3] + red[4] + red[5] + red[6] + red[7]) * 0.125f;
        if (FINAL) e_out[row] = e_acc[row] + e;
        else       e_acc[row] = e;
    }
    bf16* outr = out + (size_t)row * Dg;
    const float4* g4 = (const float4*)g;
    const float4* bt4 = (const float4*)bta;
    const float4* xo4 = OUTER ? (const float4*)(xouter + (size_t)row * Dg) : nullptr;
    float sB = 0.f, sB2 = 0.f;
    for (int c8 = tid; c8 < n8; c8 += 256) {
        float xi[8];
        b8f(*(const bf16x8*)(xir + c8 * 8), xi);
        float4 gg0 = g4[c8 * 2], gg1 = g4[c8 * 2 + 1];
        float4 bb0 = bt4[c8 * 2], bb1 = bt4[c8 * 2 + 1];
        float gv[8] = {gg0.x, gg0.y, gg0.z, gg0.w, gg1.x, gg1.y, gg1.z, gg1.w};
        float bv[8] = {bb0.x, bb0.y, bb0.z, bb0.w, bb1.x, bb1.y, bb1.z, bb1.w};
        float vv[8];
#pragma unroll
        for (int j = 0; j < 8; ++j)
            vv[j] = (y[c8 * 8 + j] - mean) * rstd * gv[j] + bv[j] + xi[j];
        if (OUTER) {
            float4 o0 = xo4[c8 * 2], o1 = xo4[c8 * 2 + 1];
            float ov[8] = {o0.x, o0.y, o0.z, o0.w, o1.x, o1.y, o1.z, o1.w};
#pragma unroll
            for (int j = 0; j < 8; ++j) vv[j] += ov[j];
        }
        *(bf16x8*)(outr + c8 * 8) = f8b(vv);
        if (FLN2) {
#pragma unroll
            for (int j = 0; j < 8; ++j) {
                y[c8 * 8 + j] = vv[j];
                sB += vv[j]; sB2 += vv[j] * vv[j];
            }
        }
    }
    if (FLN2) {
        __syncthreads();   // all reads of r1/r2 and y done
        for (int off = 32; off; off >>= 1) { sB += __shfl_down(sB, off, 64); sB2 += __shfl_down(sB2, off, 64); }
        if ((tid & 63) == 0) { r1[tid >> 6] = sB; r2[tid >> 6] = sB2; }
        __syncthreads();
        sB  = r1[0] + r1[1] + r1[2] + r1[3];
        sB2 = r2[0] + r2[1] + r2[2] + r2[3];
        float mean2 = sB / Dg;
        float rstd2 = rsqrtf(sB2 / Dg - mean2 * mean2 + 1e-5f);
        bf16* o2r = out2 + (size_t)row * Dg;
        const float4* g24 = (const float4*)g2;
        const float4* b24 = (const float4*)b2;
        for (int c8 = tid; c8 < n8; c8 += 256) {
            float4 gg0 = g24[c8 * 2], gg1 = g24[c8 * 2 + 1];
            float4 bb0 = b24[c8 * 2], bb1 = b24[c8 * 2 + 1];
            float gv[8] = {gg0.x, gg0.y, gg0.z, gg0.w, gg1.x, gg1.y, gg1.z, gg1.w};
            float bv[8] = {bb0.x, bb0.y, bb0.z, bb0.w, bb1.x, bb1.y, bb1.z, bb1.w};
            float vv[8];
#pragma unroll
            for (int j = 0; j < 8; ++j)
                vv[j] = (y[c8 * 8 + j] - mean2) * rstd2 * gv[j] + bv[j];
            *(bf16x8*)(o2r + c8 * 8) = f8b(vv);
        }
    }
}

extern "C" void kernel_launch(void* const* d_in, const int* in_sizes, int n_in,
                              void* d_out, int out_size, void* d_ws, size_t ws_size,
                              hipStream_t stream) {
    (void)in_sizes; (void)n_in; (void)out_size;
    const int M = MROWS;
    const size_t S_D = (size_t)M * DMODEL;
    const size_t S_H = (size_t)M * DHID;

    const float* x      = (const float*)d_in[0];
    const float* qkv_w  = (const float*)d_in[1];
    const float* qkv_b  = (const float*)d_in[2];
    const float* proj_w = (const float*)d_in[3];
    const float* proj_b = (const float*)d_in[4];
    const float* n1g    = (const float*)d_in[5];
    const float* n1b    = (const float*)d_in[6];
    const float* n2g    = (const float*)d_in[7];
    const float* n2b    = (const float*)d_in[8];
    const float* wa     = (const float*)d_in[9];
    const float* ba     = (const float*)d_in[10];
    const float* sca    = (const float*)d_in[11];
    const float* lga    = (const float*)d_in[12];
    const float* lba    = (const float*)d_in[13];
    const float* wm     = (const float*)d_in[14];
    const float* bm     = (const float*)d_in[15];
    const float* scm    = (const float*)d_in[16];
    const float* lgm    = (const float*)d_in[17];
    const float* lbm    = (const float*)d_in[18];
    const float* f1w    = (const float*)d_in[19];
    const float* f1b    = (const float*)d_in[20];
    const float* f2w    = (const float*)d_in[21];
    const float* f2b    = (const float*)d_in[22];
    const float* eps_a  = (const float*)d_in[23];
    const float* eps_m  = (const float*)d_in[24];

    float* out_x = (float*)d_out;          // M*768 fp32
    float* out_e = out_x + S_D;            // M fp32 (e1+e2)

    bf16* R1 = (bf16*)d_ws;
    bf16* R2 = R1 + S_H;
    bf16* R3 = R2 + S_H;
    float* E = (float*)(R3 + S_D);

    const size_t n_qkv = (size_t)2304 * 768, n_proj = (size_t)768 * 768,
                 n_wa = (size_t)768 * 768, n_wm = (size_t)3072 * 3072,
                 n_f1 = (size_t)3072 * 768, n_f2 = (size_t)768 * 3072;
    const size_t base_bytes = (2 * S_H + S_D) * 2 + (size_t)M * 4;
    const size_t w_elems = n_qkv + n_proj + n_wa + n_wm + n_f1 + n_f2;
    const bool cache_w = ws_size >= base_bytes + w_elems * 2;

    short* WB    = (short*)((char*)d_ws + base_bytes);
    short* wb_qkv = WB;
    short* wb_proj = wb_qkv + n_qkv;
    short* wb_wa  = wb_proj + n_proj;
    short* wb_wm  = wb_wa + n_wa;
    short* wb_f1  = wb_wm + n_wm;
    short* wb_f2  = wb_f1 + n_f1;

    const int GY = (M + 127) / 128;   // 99
    const size_t lds_a = (DMODEL + 96) * sizeof(float);
    const size_t lds_m = (DHID + 96) * sizeof(float);

    if (cache_w) {
        cvt_all_kernel<<<(4276224 + 255) / 256, 256, 0, stream>>>(
            qkv_w, proj_w, wa, wm, f1w, f2w, WB);
        ln1_kernel<<<M, 256, 0, stream>>>(x, n1g, n1b, R1, DMODEL);
        gemm_bf<0, bf16><<<dim3(2304 / 128, GY), 256, 0, stream>>>(
            (const short*)R1, wb_qkv, qkv_b, nullptr, R2, M, 2304, DMODEL);
        attn_mfma<<<64 * 8, 256, 0, stream>>>(R2, R1);
        gemm_bf<0, bf16><<<dim3(DMODEL / 128, GY), 256, 0, stream>>>(
            (const short*)R1, wb_proj, proj_b, nullptr, R2, M, DMODEL, DMODEL);
        gemm_bf<0, bf16><<<dim3(DMODEL / 128, GY), 256, 0, stream>>>(
            (const short*)R2, wb_wa, ba, nullptr, R1, M, DMODEL, DMODEL);
        // adapter-A + fused LN2: x_new -> R3, LN2(x_new) -> R2, e1 -> E
        adapter_finish<true, false, true><<<M, 256, lds_a, stream>>>(
            R1, R2, x, eps_a, sca, lga, lba, R3, E, nullptr, n2g, n2b, R2, DMODEL);
        gemm_bf<1, bf16><<<dim3(DHID / 128, GY), 256, 0, stream>>>(
            (const short*)R2, wb_f1, f1b, nullptr, R1, M, DHID, DMODEL);
        gemm_bf<0, bf16><<<dim3(DHID / 128, GY), 256, 0, stream>>>(
            (const short*)R1, wb_wm, bm, nullptr, R2, M, DHID, DHID);
        adapter_finish<false, true, false><<<M, 256, lds_m, stream>>>(
            R2, R1, nullptr, eps_m, scm, lgm, lbm, R1, E, out_e, nullptr, nullptr, nullptr, DHID);
        gemm_bf<2, float><<<dim3(DMODEL / 128, GY), 256, 0, stream>>>(
            (const short*)R1, wb_f2, f2b, R3, out_x, M, DMODEL, DHID);
    } else {
        ln1_kernel<<<M, 256, 0, stream>>>(x, n1g, n1b, R1, DMODEL);
        gemm_f32b<0, bf16><<<dim3(2304 / 128, GY), 256, 0, stream>>>(
            (const short*)R1, qkv_w, qkv_b, nullptr, R2, M, 2304, DMODEL);
        attn_mfma<<<64 * 8, 256, 0, stream>>>(R2, R1);
        gemm_f32b<0, bf16><<<dim3(DMODEL / 128, GY), 256, 0, stream>>>(
            (const short*)R1, proj_w, proj_b, nullptr, R2, M, DMODEL, DMODEL);
        gemm_f32b<0, bf16><<<dim3(DMODEL / 128, GY), 256, 0, stream>>>(
            (const short*)R2, wa, ba, nullptr, R1, M, DMODEL, DMODEL);
        adapter_finish<true, false, true><<<M, 256, lds_a, stream>>>(
            R1, R2, x, eps_a, sca, lga, lba, R3, E, nullptr, n2g, n2b, R2, DMODEL);
        gemm_f32b<1, bf16><<<dim3(DHID / 128, GY), 256, 0, stream>>>(
            (const short*)R2, f1w, f1b, nullptr, R1, M, DHID, DMODEL);
        gemm_f32b<0, bf16><<<dim3(DHID / 128, GY), 256, 0, stream>>>(
            (const short*)R1, wm, bm, nullptr, R2, M, DHID, DHID);
        adapter_finish<false, true, false><<<M, 256, lds_m, stream>>>(
            R2, R1, nullptr, eps_m, scm, lgm, lbm, R1, E, out_e, nullptr, nullptr, nullptr, DHID);
        gemm_f32b<2, float><<<dim3(DMODEL / 128, GY), 256, 0, stream>>>(
            (const short*)R1, f2w, f2b, R3, out_x, M, DMODEL, DHID);
    }
}